// Round 5
// baseline (188.443 us; speedup 1.0000x reference)
//
#include <hip/hip_runtime.h>
#include <hip/hip_bf16.h>
#include <math.h>

#define BZ 16
#define SEQ 64
#define CID 207
#define DIN 64
#define OCN 128
#define NN (BZ*CID)        // 3312
#define NE (NN*16)         // 52992
#define ICD (CID*DIN)      // 13248
#define KW 3
#define NKSTEP 414         // ICD/32
#define NKPAD 416          // padded to 32*13
#define NKC 32             // K-split chunks
#define KSPC 13            // ksteps per chunk
#define XTOT ((size_t)BZ*SEQ*ICD)   // 13565952
#define TCH 8              // t-chunk for gather
#define NCHUNK (SEQ/TCH)   // 8
#define GDEG 256           // max in-degree (actual max ~40 for this data)

typedef __attribute__((ext_vector_type(8))) short bf16x8;
typedef __attribute__((ext_vector_type(4))) float f32x4;
typedef unsigned short u16;
typedef unsigned int u32;

__device__ __forceinline__ float bflo(u32 u) {
    u32 v = u << 16;
    return __builtin_bit_cast(float, v);
}
__device__ __forceinline__ float bfhi(u32 u) {
    u32 v = u & 0xFFFF0000u;
    return __builtin_bit_cast(float, v);
}
__device__ __forceinline__ u16 f2bf(float f) {
    __hip_bfloat16 h = __float2bfloat16(f);
    return __builtin_bit_cast(u16, h);
}
__device__ __forceinline__ u32 packbf(float f0, float f1) {
    return ((u32)f2bf(f1) << 16) | (u32)f2bf(f0);
}

// ---------------- fused x->bf16 transpose (xt[t][n][d]) + mean over t ----------------
__global__ __launch_bounds__(256) void cvtmean_kernel(const float* __restrict__ x,
                                                      u16* __restrict__ xt,
                                                      float* __restrict__ meanx) {
    int bb = blockIdx.x;            // batch
    int cg = blockIdx.y;            // c-group of 16
    int tid = threadIdx.x;
    int cl = tid >> 4;              // 0..15
    int dq = (tid & 15) << 2;       // d0 of 4
    int c = cg * 16 + cl;
    if (c >= CID) return;
    int n = bb * CID + c;
    const float* px = x + (size_t)bb * SEQ * ICD + (size_t)c * DIN + dq;
    u16* pxt = xt + (size_t)n * DIN + dq;
    float ax = 0.f, ay = 0.f, az = 0.f, aw = 0.f;
    #pragma unroll 4
    for (int t = 0; t < SEQ; ++t) {
        float4 v = *(const float4*)(px + (size_t)t * ICD);
        ax += v.x; ay += v.y; az += v.z; aw += v.w;
        uint2 w2;
        w2.x = packbf(v.x, v.y);
        w2.y = packbf(v.z, v.w);
        *(uint2*)(pxt + (size_t)t * NN * DIN) = w2;
    }
    const float s = 1.0f / SEQ;
    float4 m4 = make_float4(ax * s, ay * s, az * s, aw * s);
    *(float4*)(meanx + (size_t)n * DIN + dq) = m4;
}

// ---------------- q/k projection ----------------
__global__ __launch_bounds__(128) void qk_kernel(const float* __restrict__ meanx,
                                                 const float* __restrict__ Wq,
                                                 const float* __restrict__ bq,
                                                 const float* __restrict__ Wk,
                                                 const float* __restrict__ bk,
                                                 float* __restrict__ q,
                                                 float* __restrict__ k) {
    __shared__ float ms[8][DIN];
    int n0 = blockIdx.x * 8;
    int tid = threadIdx.x;
    for (int i = tid; i < 8 * DIN; i += 128) {
        int nn = n0 + (i >> 6);
        ms[i >> 6][i & 63] = (nn < NN) ? meanx[(size_t)nn * DIN + (i & 63)] : 0.f;
    }
    __syncthreads();
    int j = tid;
    float accq[8], acck[8];
    float bqv = bq[j], bkv = bk[j];
    #pragma unroll
    for (int r = 0; r < 8; ++r) { accq[r] = bqv; acck[r] = bkv; }
    for (int d = 0; d < DIN; ++d) {
        float wq = Wq[d * OCN + j], wk = Wk[d * OCN + j];
        #pragma unroll
        for (int r = 0; r < 8; ++r) {
            float mv = ms[r][d];
            accq[r] += mv * wq;
            acck[r] += mv * wk;
        }
    }
    const float qscale = 0.088388347648318447f;  // 1/sqrt(128)
    #pragma unroll
    for (int r = 0; r < 8; ++r) {
        int nn = n0 + r;
        if (nn < NN) {
            q[(size_t)nn * OCN + j] = accq[r] * qscale;
            k[(size_t)nn * OCN + j] = acck[r];
        }
    }
}

// ---------------- CSR build ----------------
__global__ __launch_bounds__(256) void hist_kernel(const int* __restrict__ dst,
                                                   int* __restrict__ cnt) {
    int e = blockIdx.x * 256 + threadIdx.x;
    if (e < NE) atomicAdd(&cnt[dst[e]], 1);
}

__global__ __launch_bounds__(1024) void scan_kernel(const int* __restrict__ cnt,
                                                    int* __restrict__ offs) {
    __shared__ int sums[1024], sums2[1024];
    int tid = threadIdx.x;
    int base = tid * 4;
    int v[4];
    #pragma unroll
    for (int i = 0; i < 4; ++i) v[i] = (base + i < NN) ? cnt[base + i] : 0;
    sums[tid] = v[0] + v[1] + v[2] + v[3];
    __syncthreads();
    int* a = sums;
    int* b2 = sums2;
    for (int off = 1; off < 1024; off <<= 1) {
        int val = a[tid] + ((tid >= off) ? a[tid - off] : 0);
        b2[tid] = val;
        __syncthreads();
        int* t = a; a = b2; b2 = t;
    }
    int prev = (tid > 0) ? a[tid - 1] : 0;
    int run = prev;
    #pragma unroll
    for (int i = 0; i < 4; ++i) {
        if (base + i <= NN) offs[base + i] = run;
        run += v[i];
    }
}

__global__ __launch_bounds__(256) void scatter_kernel(const int* __restrict__ src,
                                                      const int* __restrict__ dst,
                                                      const int* __restrict__ offs,
                                                      int* __restrict__ fill,
                                                      int* __restrict__ csr_src) {
    int e = blockIdx.x * 256 + threadIdx.x;
    if (e >= NE) return;
    int d0 = dst[e];
    int pos = offs[d0] + atomicAdd(&fill[d0], 1);
    csr_src[pos] = src[e];
}

// ---------------- per-edge attention weights (scores + segment softmax) ----------------
__global__ __launch_bounds__(256) void alpha_kernel(const float* __restrict__ q,
                                                    const float* __restrict__ k,
                                                    const int* __restrict__ offs,
                                                    const int* __restrict__ csr,
                                                    float* __restrict__ alpha) {
    __shared__ float qs[OCN];
    __shared__ float sc[GDEG];
    __shared__ int sidx[GDEG];
    int n = blockIdx.x;
    int start = offs[n];
    int deg = offs[n + 1] - start;
    if (deg > GDEG) deg = GDEG;
    int tid = threadIdx.x;
    if (tid < OCN) qs[tid] = q[(size_t)n * OCN + tid];
    for (int i = tid; i < deg; i += 256) sidx[i] = csr[start + i];
    __syncthreads();
    int lane = tid & 63;
    int wv = tid >> 6;
    for (int i = wv; i < deg; i += 4) {
        const float* kk = k + (size_t)sidx[i] * OCN;
        float p = kk[lane] * qs[lane] + kk[lane + 64] * qs[lane + 64];
        #pragma unroll
        for (int off = 32; off; off >>= 1) p += __shfl_down(p, off);
        if (lane == 0) sc[i] = p;
    }
    __syncthreads();
    float m = -1e30f;
    for (int i = 0; i < deg; ++i) m = fmaxf(m, sc[i]);
    __syncthreads();
    for (int i = tid; i < deg; i += 256) sc[i] = __expf(sc[i] - m);
    __syncthreads();
    float ssum = 0.f;
    for (int i = 0; i < deg; ++i) ssum += sc[i];
    float inv = (deg > 0) ? (1.0f / ssum) : 0.f;
    for (int i = tid; i < deg; i += 256) alpha[start + i] = sc[i] * inv;
}

// ---------------- t-chunked weighted gather, XCD-pinned chunks ----------------
__global__ __launch_bounds__(256) void gather2_kernel(const u16* __restrict__ xt,
                                                      const float* __restrict__ alpha,
                                                      const int* __restrict__ offs,
                                                      const int* __restrict__ csr,
                                                      u16* __restrict__ yb) {
    __shared__ int sidx[GDEG];
    __shared__ float sal[GDEG];
    __shared__ float sacc[4][TCH * DIN];
    int bid = blockIdx.x;
    int ch = bid & 7;
    int n = bid >> 3;
    int t0 = ch * TCH;
    int b = n / CID, c = n - b * CID;
    int start = offs[n];
    int deg = offs[n + 1] - start;
    if (deg > GDEG) deg = GDEG;
    int tid = threadIdx.x;
    for (int i = tid; i < deg; i += 256) {
        sidx[i] = csr[start + i] << 6;   // element offset s*DIN
        sal[i] = alpha[start + i];
    }
    __syncthreads();
    int ew = tid >> 6;          // edge-worker wave 0..3
    int lane = tid & 63;
    int t = lane >> 3;          // 0..7
    int dg = lane & 7;          // 8 d's each (16B)
    float acc[8];
    #pragma unroll
    for (int j = 0; j < 8; ++j) acc[j] = 0.f;
    const u16* xbase = xt + ((size_t)(t0 + t) * NN) * DIN + (dg << 3);
    for (int i = ew; i < deg; i += 4) {
        int so = sidx[i];
        float a = sal[i];
        uint4 v = *(const uint4*)(xbase + so);
        acc[0] += a * bflo(v.x); acc[1] += a * bfhi(v.x);
        acc[2] += a * bflo(v.y); acc[3] += a * bfhi(v.y);
        acc[4] += a * bflo(v.z); acc[5] += a * bfhi(v.z);
        acc[6] += a * bflo(v.w); acc[7] += a * bfhi(v.w);
    }
    int base = t * DIN + (dg << 3);
    #pragma unroll
    for (int j = 0; j < 8; ++j) sacc[ew][base + j] = acc[j];
    __syncthreads();
    int e = tid * 2;
    int tt = e >> 6, d = e & 63;
    float v0 = sacc[0][e] + sacc[1][e] + sacc[2][e] + sacc[3][e];
    float v1 = sacc[0][e + 1] + sacc[1][e + 1] + sacc[2][e + 1] + sacc[3][e + 1];
    u32 pw = packbf(v0, v1);
    *(u32*)(yb + ((size_t)b * SEQ + t0 + tt) * ICD + c * DIN + d) = pw;
}

// ---------------- conv weight -> MFMA B-fragment layout (bf16) ----------------
__global__ __launch_bounds__(256) void wprep_kernel(const float* __restrict__ cw,
                                                    u16* __restrict__ wf) {
    __shared__ float s_cw[128][100];  // 96 cols + pad
    int kstep = blockIdx.x;           // 0..415
    int ic0 = kstep * 32;
    int tid = threadIdx.x;
    {
        int oc = tid >> 1, hf = tid & 1;
        const float* src = cw + (size_t)oc * (ICD * KW) + (size_t)ic0 * 3 + hf * 48;
        #pragma unroll
        for (int u = 0; u < 48; ++u) {
            int col = hf * 48 + u;
            int ic = ic0 + col / 3;
            float v = 0.f;
            if (ic < ICD) v = src[u];
            s_cw[oc][col] = v;
        }
    }
    __syncthreads();
    #pragma unroll
    for (int r = 0; r < 6; ++r) {
        int f = tid + 256 * r;        // 0..1535
        int lane = f & 63;
        int nt = (f >> 6) & 7;
        int w = f >> 9;
        int row = nt * 16 + (lane & 15);
        int cb = 8 * (lane >> 4);
        uint4 o;
        u32 p[4];
        #pragma unroll
        for (int pj = 0; pj < 4; ++pj) {
            float v0 = s_cw[row][(cb + 2 * pj) * 3 + w];
            float v1 = s_cw[row][(cb + 2 * pj + 1) * 3 + w];
            p[pj] = packbf(v0, v1);
        }
        o.x = p[0]; o.y = p[1]; o.z = p[2]; o.w = p[3];
        size_t off = (((size_t)(kstep * 3 + w) * 8 + nt) * 64 + lane) * 8;
        *(uint4*)(wf + off) = o;
    }
}

// ---------------- conv1d as MFMA GEMM, split-K(XCD-pinned) + split-T, atomic epilogue ----------------
// bid = (kc&7) + 8*( (b*2+th) + 32*(kc>>3) )  -> XCD (bid&7) sees only kc === xcd (mod 8):
// 4 kc-slices of wf (1.3 MB) stay L2-resident per XCD.
// block: 32 t x 128 oc; waves: (wid&1)=t-subtile, (wid>>1)=oc-half.
__global__ __launch_bounds__(256) void conv_kernel(const u16* __restrict__ yb,
                                                   const u16* __restrict__ wf,
                                                   float* __restrict__ out) {
    int bid = blockIdx.x;
    int xcd = bid & 7;
    int rest = bid >> 3;               // 0..127
    int khi = rest >> 5;               // kc>>3: 0..3
    int sub = rest & 31;               // b*2+th
    int kc = xcd + (khi << 3);
    int b = sub >> 1;
    int th = sub & 1;
    int tid = threadIdx.x;
    int lane = tid & 63;
    int wid = tid >> 6;
    int t0 = th * 32 + (wid & 1) * 16;
    int nh = wid >> 1;                 // oc half
    int lrow = lane & 15;              // A row (t_local), D col (oc_local)
    int lq = lane >> 4;                // k-group / D row group
    f32x4 acc[4];
    #pragma unroll
    for (int n = 0; n < 4; ++n) acc[n] = (f32x4){0.f, 0.f, 0.f, 0.f};

    const u16* ybase = yb + (size_t)b * SEQ * ICD + lq * 8;
    for (int ks = 0; ks < KSPC; ++ks) {
        int kstep = kc * KSPC + ks;
        int ic0 = kstep * 32;
        bf16x8 a[3];
        #pragma unroll
        for (int w = 0; w < 3; ++w) {
            int ts = t0 + lrow + w - 1;
            bf16x8 av = {0, 0, 0, 0, 0, 0, 0, 0};
            if ((unsigned)ts < SEQ)
                av = *(const bf16x8*)(ybase + (size_t)ts * ICD + ic0);
            a[w] = av;
        }
        const u16* wfp = wf + (size_t)kstep * 3 * 8 * 64 * 8 + lane * 8;
        #pragma unroll
        for (int w = 0; w < 3; ++w) {
            #pragma unroll
            for (int n = 0; n < 4; ++n) {
                bf16x8 bv = *(const bf16x8*)(wfp + (size_t)((w * 8 + nh * 4 + n) * 64) * 8);
                acc[n] = __builtin_amdgcn_mfma_f32_16x16x32_bf16(a[w], bv, acc[n], 0, 0, 0);
            }
        }
    }
    float* po = out + (size_t)b * SEQ * OCN + nh * 64;
    #pragma unroll
    for (int n = 0; n < 4; ++n) {
        #pragma unroll
        for (int r = 0; r < 4; ++r) {
            int t = t0 + lq * 4 + r;
            atomicAdd(&po[(size_t)t * OCN + n * 16 + lrow], acc[n][r]);
        }
    }
}

extern "C" void kernel_launch(void* const* d_in, const int* in_sizes, int n_in,
                              void* d_out, int out_size, void* d_ws, size_t ws_size,
                              hipStream_t stream) {
    const float* x   = (const float*)d_in[0];
    const float* Wq  = (const float*)d_in[1];
    const float* bqv = (const float*)d_in[2];
    const float* Wk  = (const float*)d_in[3];
    const float* bkv = (const float*)d_in[4];
    const float* cw  = (const float*)d_in[5];
    const int* esrc  = (const int*)d_in[6];
    const int* edst  = (const int*)d_in[7];

    char* ws = (char*)d_ws;
    size_t o = 0;
    auto alloc = [&](size_t bytes) {
        void* p = ws + o;
        o += (bytes + 255) & ~(size_t)255;
        return p;
    };
    u16*   xt    = (u16*)alloc(XTOT * 2);                 // 27.1 MB
    u16*   yb    = (u16*)alloc(XTOT * 2);                 // 27.1 MB
    u16*   wf    = (u16*)alloc((size_t)NKPAD * 3 * 8 * 64 * 8 * 2);  // 10.2 MB
    float* meanx = (float*)alloc((size_t)NN * DIN * 4);
    float* q     = (float*)alloc((size_t)NN * OCN * 4);
    float* k     = (float*)alloc((size_t)NN * OCN * 4);
    int*   cnt   = (int*)alloc(4096 * 4);
    int*   fill  = (int*)alloc(4096 * 4);
    int*   offs  = (int*)alloc(4352 * 4);
    int*   csr   = (int*)alloc((size_t)NE * 4);
    float* alpha = (float*)alloc((size_t)NE * 4);

    hipMemsetAsync(cnt, 0, 4096 * 4, stream);
    hipMemsetAsync(fill, 0, 4096 * 4, stream);
    hipMemsetAsync(d_out, 0, (size_t)out_size * 4, stream);

    cvtmean_kernel<<<dim3(16, 13), dim3(256), 0, stream>>>(x, xt, meanx);
    qk_kernel<<<dim3(NN / 8), dim3(128), 0, stream>>>(meanx, Wq, bqv, Wk, bkv, q, k);
    hist_kernel<<<dim3((NE + 255) / 256), dim3(256), 0, stream>>>(edst, cnt);
    scan_kernel<<<dim3(1), dim3(1024), 0, stream>>>(cnt, offs);
    scatter_kernel<<<dim3((NE + 255) / 256), dim3(256), 0, stream>>>(esrc, edst, offs, fill, csr);
    wprep_kernel<<<dim3(NKPAD), dim3(256), 0, stream>>>(cw, wf);
    alpha_kernel<<<dim3(NN), dim3(256), 0, stream>>>(q, k, offs, csr, alpha);
    gather2_kernel<<<dim3(NN * NCHUNK), dim3(256), 0, stream>>>(xt, alpha, offs, csr, yb);
    conv_kernel<<<dim3(16 * NKC * 2), dim3(256), 0, stream>>>(yb, wf, (float*)d_out);
}

// Round 6
// 174.025 us; speedup vs baseline: 1.0828x; 1.0828x over previous
//
#include <hip/hip_runtime.h>
#include <hip/hip_bf16.h>
#include <math.h>

#define BZ 16
#define SEQ 64
#define CID 207
#define DIN 64
#define OCN 128
#define NN (BZ*CID)        // 3312
#define NE (NN*16)         // 52992
#define ICD (CID*DIN)      // 13248
#define KW 3
#define NKSTEP 414         // ICD/32
#define NKPAD 416          // padded to 32*13
#define NKC 32             // K-split chunks
#define KSPC 13            // ksteps per chunk
#define XTOT ((size_t)BZ*SEQ*ICD)   // 13565952
#define TCH 8              // t-chunk for gather
#define NCHUNK (SEQ/TCH)   // 8
#define GDEG 256           // max in-degree (actual max ~40 for this data)
#define WFSTEP (3*8*64*8)  // wf elems per kstep = 12288

typedef __attribute__((ext_vector_type(8))) short bf16x8;
typedef __attribute__((ext_vector_type(4))) float f32x4;
typedef unsigned short u16;
typedef unsigned int u32;

__device__ __forceinline__ float bflo(u32 u) {
    u32 v = u << 16;
    return __builtin_bit_cast(float, v);
}
__device__ __forceinline__ float bfhi(u32 u) {
    u32 v = u & 0xFFFF0000u;
    return __builtin_bit_cast(float, v);
}
__device__ __forceinline__ u16 f2bf(float f) {
    __hip_bfloat16 h = __float2bfloat16(f);
    return __builtin_bit_cast(u16, h);
}
__device__ __forceinline__ u32 packbf(float f0, float f1) {
    return ((u32)f2bf(f1) << 16) | (u32)f2bf(f0);
}

// ---------------- fused x->bf16 transpose (xt[t][n][d]) + mean over t ----------------
__global__ __launch_bounds__(256) void cvtmean_kernel(const float* __restrict__ x,
                                                      u16* __restrict__ xt,
                                                      float* __restrict__ meanx) {
    int bb = blockIdx.x;            // batch
    int cg = blockIdx.y;            // c-group of 16
    int tid = threadIdx.x;
    int cl = tid >> 4;              // 0..15
    int dq = (tid & 15) << 2;       // d0 of 4
    int c = cg * 16 + cl;
    if (c >= CID) return;
    int n = bb * CID + c;
    const float* px = x + (size_t)bb * SEQ * ICD + (size_t)c * DIN + dq;
    u16* pxt = xt + (size_t)n * DIN + dq;
    float ax = 0.f, ay = 0.f, az = 0.f, aw = 0.f;
    #pragma unroll 4
    for (int t = 0; t < SEQ; ++t) {
        float4 v = *(const float4*)(px + (size_t)t * ICD);
        ax += v.x; ay += v.y; az += v.z; aw += v.w;
        uint2 w2;
        w2.x = packbf(v.x, v.y);
        w2.y = packbf(v.z, v.w);
        *(uint2*)(pxt + (size_t)t * NN * DIN) = w2;
    }
    const float s = 1.0f / SEQ;
    float4 m4 = make_float4(ax * s, ay * s, az * s, aw * s);
    *(float4*)(meanx + (size_t)n * DIN + dq) = m4;
}

// ---------------- q/k projection ----------------
__global__ __launch_bounds__(128) void qk_kernel(const float* __restrict__ meanx,
                                                 const float* __restrict__ Wq,
                                                 const float* __restrict__ bq,
                                                 const float* __restrict__ Wk,
                                                 const float* __restrict__ bk,
                                                 float* __restrict__ q,
                                                 float* __restrict__ k) {
    __shared__ float ms[8][DIN];
    int n0 = blockIdx.x * 8;
    int tid = threadIdx.x;
    for (int i = tid; i < 8 * DIN; i += 128) {
        int nn = n0 + (i >> 6);
        ms[i >> 6][i & 63] = (nn < NN) ? meanx[(size_t)nn * DIN + (i & 63)] : 0.f;
    }
    __syncthreads();
    int j = tid;
    float accq[8], acck[8];
    float bqv = bq[j], bkv = bk[j];
    #pragma unroll
    for (int r = 0; r < 8; ++r) { accq[r] = bqv; acck[r] = bkv; }
    for (int d = 0; d < DIN; ++d) {
        float wq = Wq[d * OCN + j], wk = Wk[d * OCN + j];
        #pragma unroll
        for (int r = 0; r < 8; ++r) {
            float mv = ms[r][d];
            accq[r] += mv * wq;
            acck[r] += mv * wk;
        }
    }
    const float qscale = 0.088388347648318447f;  // 1/sqrt(128)
    #pragma unroll
    for (int r = 0; r < 8; ++r) {
        int nn = n0 + r;
        if (nn < NN) {
            q[(size_t)nn * OCN + j] = accq[r] * qscale;
            k[(size_t)nn * OCN + j] = acck[r];
        }
    }
}

// ---------------- CSR build ----------------
__global__ __launch_bounds__(256) void hist_kernel(const int* __restrict__ dst,
                                                   int* __restrict__ cnt) {
    int e = blockIdx.x * 256 + threadIdx.x;
    if (e < NE) atomicAdd(&cnt[dst[e]], 1);
}

__global__ __launch_bounds__(1024) void scan_kernel(const int* __restrict__ cnt,
                                                    int* __restrict__ offs) {
    __shared__ int sums[1024], sums2[1024];
    int tid = threadIdx.x;
    int base = tid * 4;
    int v[4];
    #pragma unroll
    for (int i = 0; i < 4; ++i) v[i] = (base + i < NN) ? cnt[base + i] : 0;
    sums[tid] = v[0] + v[1] + v[2] + v[3];
    __syncthreads();
    int* a = sums;
    int* b2 = sums2;
    for (int off = 1; off < 1024; off <<= 1) {
        int val = a[tid] + ((tid >= off) ? a[tid - off] : 0);
        b2[tid] = val;
        __syncthreads();
        int* t = a; a = b2; b2 = t;
    }
    int prev = (tid > 0) ? a[tid - 1] : 0;
    int run = prev;
    #pragma unroll
    for (int i = 0; i < 4; ++i) {
        if (base + i <= NN) offs[base + i] = run;
        run += v[i];
    }
}

__global__ __launch_bounds__(256) void scatter_kernel(const int* __restrict__ src,
                                                      const int* __restrict__ dst,
                                                      const int* __restrict__ offs,
                                                      int* __restrict__ fill,
                                                      int* __restrict__ csr_src) {
    int e = blockIdx.x * 256 + threadIdx.x;
    if (e >= NE) return;
    int d0 = dst[e];
    int pos = offs[d0] + atomicAdd(&fill[d0], 1);
    csr_src[pos] = src[e];
}

// ---------------- per-edge attention weights (scores + segment softmax) ----------------
__global__ __launch_bounds__(256) void alpha_kernel(const float* __restrict__ q,
                                                    const float* __restrict__ k,
                                                    const int* __restrict__ offs,
                                                    const int* __restrict__ csr,
                                                    float* __restrict__ alpha) {
    __shared__ float qs[OCN];
    __shared__ float sc[GDEG];
    __shared__ int sidx[GDEG];
    int n = blockIdx.x;
    int start = offs[n];
    int deg = offs[n + 1] - start;
    if (deg > GDEG) deg = GDEG;
    int tid = threadIdx.x;
    if (tid < OCN) qs[tid] = q[(size_t)n * OCN + tid];
    for (int i = tid; i < deg; i += 256) sidx[i] = csr[start + i];
    __syncthreads();
    int lane = tid & 63;
    int wv = tid >> 6;
    for (int i = wv; i < deg; i += 4) {
        const float* kk = k + (size_t)sidx[i] * OCN;
        float p = kk[lane] * qs[lane] + kk[lane + 64] * qs[lane + 64];
        #pragma unroll
        for (int off = 32; off; off >>= 1) p += __shfl_down(p, off);
        if (lane == 0) sc[i] = p;
    }
    __syncthreads();
    float m = -1e30f;
    for (int i = 0; i < deg; ++i) m = fmaxf(m, sc[i]);
    __syncthreads();
    for (int i = tid; i < deg; i += 256) sc[i] = __expf(sc[i] - m);
    __syncthreads();
    float ssum = 0.f;
    for (int i = 0; i < deg; ++i) ssum += sc[i];
    float inv = (deg > 0) ? (1.0f / ssum) : 0.f;
    for (int i = tid; i < deg; i += 256) alpha[start + i] = sc[i] * inv;
}

// ---------------- t-chunked weighted gather, XCD-pinned chunks ----------------
__global__ __launch_bounds__(256) void gather2_kernel(const u16* __restrict__ xt,
                                                      const float* __restrict__ alpha,
                                                      const int* __restrict__ offs,
                                                      const int* __restrict__ csr,
                                                      u16* __restrict__ yb) {
    __shared__ int sidx[GDEG];
    __shared__ float sal[GDEG];
    __shared__ float sacc[4][TCH * DIN];
    int bid = blockIdx.x;
    int ch = bid & 7;
    int n = bid >> 3;
    int t0 = ch * TCH;
    int b = n / CID, c = n - b * CID;
    int start = offs[n];
    int deg = offs[n + 1] - start;
    if (deg > GDEG) deg = GDEG;
    int tid = threadIdx.x;
    for (int i = tid; i < deg; i += 256) {
        sidx[i] = csr[start + i] << 6;   // element offset s*DIN
        sal[i] = alpha[start + i];
    }
    __syncthreads();
    int ew = tid >> 6;          // edge-worker wave 0..3
    int lane = tid & 63;
    int t = lane >> 3;          // 0..7
    int dg = lane & 7;          // 8 d's each (16B)
    float acc[8];
    #pragma unroll
    for (int j = 0; j < 8; ++j) acc[j] = 0.f;
    const u16* xbase = xt + ((size_t)(t0 + t) * NN) * DIN + (dg << 3);
    for (int i = ew; i < deg; i += 4) {
        int so = sidx[i];
        float a = sal[i];
        uint4 v = *(const uint4*)(xbase + so);
        acc[0] += a * bflo(v.x); acc[1] += a * bfhi(v.x);
        acc[2] += a * bflo(v.y); acc[3] += a * bfhi(v.y);
        acc[4] += a * bflo(v.z); acc[5] += a * bfhi(v.z);
        acc[6] += a * bflo(v.w); acc[7] += a * bfhi(v.w);
    }
    int base = t * DIN + (dg << 3);
    #pragma unroll
    for (int j = 0; j < 8; ++j) sacc[ew][base + j] = acc[j];
    __syncthreads();
    int e = tid * 2;
    int tt = e >> 6, d = e & 63;
    float v0 = sacc[0][e] + sacc[1][e] + sacc[2][e] + sacc[3][e];
    float v1 = sacc[0][e + 1] + sacc[1][e + 1] + sacc[2][e + 1] + sacc[3][e + 1];
    u32 pw = packbf(v0, v1);
    *(u32*)(yb + ((size_t)b * SEQ + t0 + tt) * ICD + c * DIN + d) = pw;
}

// ---------------- conv weight -> MFMA B-fragment layout (bf16) ----------------
__global__ __launch_bounds__(256) void wprep_kernel(const float* __restrict__ cw,
                                                    u16* __restrict__ wf) {
    __shared__ float s_cw[128][100];  // 96 cols + pad
    int kstep = blockIdx.x;           // 0..415
    int ic0 = kstep * 32;
    int tid = threadIdx.x;
    {
        int oc = tid >> 1, hf = tid & 1;
        const float* src = cw + (size_t)oc * (ICD * KW) + (size_t)ic0 * 3 + hf * 48;
        #pragma unroll
        for (int u = 0; u < 48; ++u) {
            int col = hf * 48 + u;
            int ic = ic0 + col / 3;
            float v = 0.f;
            if (ic < ICD) v = src[u];
            s_cw[oc][col] = v;
        }
    }
    __syncthreads();
    #pragma unroll
    for (int r = 0; r < 6; ++r) {
        int f = tid + 256 * r;        // 0..1535
        int lane = f & 63;
        int nt = (f >> 6) & 7;
        int w = f >> 9;
        int row = nt * 16 + (lane & 15);
        int cb = 8 * (lane >> 4);
        uint4 o;
        u32 p[4];
        #pragma unroll
        for (int pj = 0; pj < 4; ++pj) {
            float v0 = s_cw[row][(cb + 2 * pj) * 3 + w];
            float v1 = s_cw[row][(cb + 2 * pj + 1) * 3 + w];
            p[pj] = packbf(v0, v1);
        }
        o.x = p[0]; o.y = p[1]; o.z = p[2]; o.w = p[3];
        size_t off = (((size_t)(kstep * 3 + w) * 8 + nt) * 64 + lane) * 8;
        *(uint4*)(wf + off) = o;
    }
}

// ---------------- conv1d as MFMA GEMM: 64t x 128oc per block, split-K(XCD-pinned) ----------------
// grid 512 = 8 xcd * 4 khi * 16 b ; kc = xcd + 8*khi (per-XCD wf slices L2-resident).
// wave = 32t x 64oc (2 t-tiles x 4 oc-tiles, 8 acc); 1-deep register double-buffer of A/B.
__global__ __launch_bounds__(256) void conv_kernel(const u16* __restrict__ yb,
                                                   const u16* __restrict__ wf,
                                                   float* __restrict__ partial) {
    int bid = blockIdx.x;
    int xcd = bid & 7;
    int rest = bid >> 3;               // 0..63
    int khi = rest & 3;
    int b = rest >> 2;                 // 0..15
    int kc = xcd + (khi << 3);         // 0..31
    int tid = threadIdx.x;
    int lane = tid & 63;
    int wid = tid >> 6;
    int th = wid & 1;                  // t half: 0/32
    int nh = wid >> 1;                 // oc half: 0/64
    int lrow = lane & 15;
    int lq = lane >> 4;
    int tbase = th * 32;

    f32x4 acc[2][4];
    #pragma unroll
    for (int tt = 0; tt < 2; ++tt)
        #pragma unroll
        for (int n = 0; n < 4; ++n) acc[tt][n] = (f32x4){0.f, 0.f, 0.f, 0.f};

    const u16* ybA = yb + (size_t)b * SEQ * ICD + lq * 8;
    const u16* wfL = wf + (size_t)lane * 8 + ((size_t)nh * 4 * 64) * 8;
    int ks0 = kc * KSPC;

    bf16x8 aA[6], bA[12], aB[6], bB[12];

#define LOAD_AB(aR, bR, KS) do {                                              \
    int kstep_ = ks0 + (KS);                                                  \
    int ic0_ = kstep_ * 32;                                                   \
    _Pragma("unroll")                                                         \
    for (int tt_ = 0; tt_ < 2; ++tt_) {                                       \
        _Pragma("unroll")                                                     \
        for (int w_ = 0; w_ < 3; ++w_) {                                      \
            int ts_ = tbase + tt_ * 16 + lrow + w_ - 1;                       \
            bf16x8 av_ = {0, 0, 0, 0, 0, 0, 0, 0};                            \
            if ((unsigned)ts_ < SEQ)                                          \
                av_ = *(const bf16x8*)(ybA + (size_t)ts_ * ICD + ic0_);       \
            aR[tt_ * 3 + w_] = av_;                                           \
        }                                                                     \
    }                                                                         \
    const u16* wfp_ = wfL + (size_t)kstep_ * WFSTEP;                          \
    _Pragma("unroll")                                                         \
    for (int w_ = 0; w_ < 3; ++w_) {                                          \
        _Pragma("unroll")                                                     \
        for (int n_ = 0; n_ < 4; ++n_)                                        \
            bR[w_ * 4 + n_] = *(const bf16x8*)(wfp_ + (size_t)((w_ * 8 + n_) * 64) * 8); \
    }                                                                         \
} while (0)

#define COMPUTE(aR, bR) do {                                                  \
    _Pragma("unroll")                                                         \
    for (int w_ = 0; w_ < 3; ++w_) {                                          \
        _Pragma("unroll")                                                     \
        for (int tt_ = 0; tt_ < 2; ++tt_) {                                   \
            _Pragma("unroll")                                                 \
            for (int n_ = 0; n_ < 4; ++n_)                                    \
                acc[tt_][n_] = __builtin_amdgcn_mfma_f32_16x16x32_bf16(       \
                    aR[tt_ * 3 + w_], bR[w_ * 4 + n_], acc[tt_][n_], 0, 0, 0);\
        }                                                                     \
    }                                                                         \
} while (0)

    LOAD_AB(aA, bA, 0);
    #pragma unroll
    for (int ks = 0; ks < KSPC - 1; ks += 2) {
        LOAD_AB(aB, bB, ks + 1);
        COMPUTE(aA, bA);
        LOAD_AB(aA, bA, ks + 2);
        COMPUTE(aB, bB);
    }
    COMPUTE(aA, bA);   // ks = KSPC-1 (12)

    float* pp = partial + (size_t)kc * ((size_t)BZ * SEQ * OCN) + (size_t)b * SEQ * OCN + nh * 64;
    #pragma unroll
    for (int tt = 0; tt < 2; ++tt) {
        #pragma unroll
        for (int n = 0; n < 4; ++n) {
            #pragma unroll
            for (int r = 0; r < 4; ++r) {
                int t = tbase + tt * 16 + lq * 4 + r;
                pp[(size_t)t * OCN + n * 16 + lrow] = acc[tt][n][r];
            }
        }
    }
#undef LOAD_AB
#undef COMPUTE
}

// ---------------- split-K reduce (float4) ----------------
__global__ __launch_bounds__(256) void reduce_kernel(const float* __restrict__ partial,
                                                     float* __restrict__ out) {
    int i = (blockIdx.x * 256 + threadIdx.x) * 4;   // 131072 total
    float4 s = make_float4(0.f, 0.f, 0.f, 0.f);
    #pragma unroll
    for (int kc = 0; kc < NKC; ++kc) {
        float4 v = *(const float4*)(partial + (size_t)kc * 131072 + i);
        s.x += v.x; s.y += v.y; s.z += v.z; s.w += v.w;
    }
    *(float4*)(out + i) = s;
}

extern "C" void kernel_launch(void* const* d_in, const int* in_sizes, int n_in,
                              void* d_out, int out_size, void* d_ws, size_t ws_size,
                              hipStream_t stream) {
    const float* x   = (const float*)d_in[0];
    const float* Wq  = (const float*)d_in[1];
    const float* bqv = (const float*)d_in[2];
    const float* Wk  = (const float*)d_in[3];
    const float* bkv = (const float*)d_in[4];
    const float* cw  = (const float*)d_in[5];
    const int* esrc  = (const int*)d_in[6];
    const int* edst  = (const int*)d_in[7];

    char* ws = (char*)d_ws;
    size_t o = 0;
    auto alloc = [&](size_t bytes) {
        void* p = ws + o;
        o += (bytes + 255) & ~(size_t)255;
        return p;
    };
    u16*   xt    = (u16*)alloc(XTOT * 2);                 // 27.1 MB (aliased by partial after gather2)
    u16*   yb    = (u16*)alloc(XTOT * 2);                 // 27.1 MB
    u16*   wf    = (u16*)alloc((size_t)NKPAD * 3 * 8 * 64 * 8 * 2);  // 10.2 MB
    float* meanx = (float*)alloc((size_t)NN * DIN * 4);
    float* q     = (float*)alloc((size_t)NN * OCN * 4);
    float* k     = (float*)alloc((size_t)NN * OCN * 4);
    int*   cnt   = (int*)alloc(4096 * 4);
    int*   fill  = (int*)alloc(4096 * 4);
    int*   offs  = (int*)alloc(4352 * 4);
    int*   csr   = (int*)alloc((size_t)NE * 4);
    float* alpha = (float*)alloc((size_t)NE * 4);
    float* partial = (float*)xt;   // alias: xt dead after gather2; partial live conv->reduce (16.8 MB < 27.1 MB)

    hipMemsetAsync(cnt, 0, 4096 * 4, stream);
    hipMemsetAsync(fill, 0, 4096 * 4, stream);

    cvtmean_kernel<<<dim3(16, 13), dim3(256), 0, stream>>>(x, xt, meanx);
    qk_kernel<<<dim3(NN / 8), dim3(128), 0, stream>>>(meanx, Wq, bqv, Wk, bkv, q, k);
    hist_kernel<<<dim3((NE + 255) / 256), dim3(256), 0, stream>>>(edst, cnt);
    scan_kernel<<<dim3(1), dim3(1024), 0, stream>>>(cnt, offs);
    scatter_kernel<<<dim3((NE + 255) / 256), dim3(256), 0, stream>>>(esrc, edst, offs, fill, csr);
    wprep_kernel<<<dim3(NKPAD), dim3(256), 0, stream>>>(cw, wf);
    alpha_kernel<<<dim3(NN), dim3(256), 0, stream>>>(q, k, offs, csr, alpha);
    gather2_kernel<<<dim3(NN * NCHUNK), dim3(256), 0, stream>>>(xt, alpha, offs, csr, yb);
    conv_kernel<<<dim3(512), dim3(256), 0, stream>>>(yb, wf, partial);
    reduce_kernel<<<dim3(131072 / 4 / 256), dim3(256), 0, stream>>>(partial, (float*)d_out);
}

// Round 7
// 168.092 us; speedup vs baseline: 1.1211x; 1.0353x over previous
//
#include <hip/hip_runtime.h>
#include <hip/hip_bf16.h>
#include <math.h>

#define BZ 16
#define SEQ 64
#define CID 207
#define DIN 64
#define OCN 128
#define NN (BZ*CID)        // 3312
#define NE (NN*16)         // 52992
#define ICD (CID*DIN)      // 13248
#define KW 3
#define NKSTEP 414         // ICD/32
#define NKPAD 416          // padded to 32*13
#define NKC 32             // K-split chunks
#define KSPC 13            // ksteps per chunk
#define XTOT ((size_t)BZ*SEQ*ICD)   // 13565952
#define TCH 8              // t-chunk for gather
#define NCHUNK (SEQ/TCH)   // 8
#define GDEG 256           // max in-degree (actual max ~40 for this data)
#define WFSTEP (3*8*64*8)  // wf elems per kstep = 12288

typedef __attribute__((ext_vector_type(8))) short bf16x8;
typedef __attribute__((ext_vector_type(4))) float f32x4;
typedef unsigned short u16;
typedef unsigned int u32;

__device__ __forceinline__ float bflo(u32 u) {
    u32 v = u << 16;
    return __builtin_bit_cast(float, v);
}
__device__ __forceinline__ float bfhi(u32 u) {
    u32 v = u & 0xFFFF0000u;
    return __builtin_bit_cast(float, v);
}
__device__ __forceinline__ u16 f2bf(float f) {
    __hip_bfloat16 h = __float2bfloat16(f);
    return __builtin_bit_cast(u16, h);
}
__device__ __forceinline__ u32 packbf(float f0, float f1) {
    return ((u32)f2bf(f1) << 16) | (u32)f2bf(f0);
}

// ---------------- fused x->bf16 transpose (xt[t][n][d]) + mean over t ----------------
__global__ __launch_bounds__(256) void cvtmean_kernel(const float* __restrict__ x,
                                                      u16* __restrict__ xt,
                                                      float* __restrict__ meanx) {
    int bb = blockIdx.x;            // batch
    int cg = blockIdx.y;            // c-group of 16
    int tid = threadIdx.x;
    int cl = tid >> 4;              // 0..15
    int dq = (tid & 15) << 2;       // d0 of 4
    int c = cg * 16 + cl;
    if (c >= CID) return;
    int n = bb * CID + c;
    const float* px = x + (size_t)bb * SEQ * ICD + (size_t)c * DIN + dq;
    u16* pxt = xt + (size_t)n * DIN + dq;
    float ax = 0.f, ay = 0.f, az = 0.f, aw = 0.f;
    #pragma unroll 4
    for (int t = 0; t < SEQ; ++t) {
        float4 v = *(const float4*)(px + (size_t)t * ICD);
        ax += v.x; ay += v.y; az += v.z; aw += v.w;
        uint2 w2;
        w2.x = packbf(v.x, v.y);
        w2.y = packbf(v.z, v.w);
        *(uint2*)(pxt + (size_t)t * NN * DIN) = w2;
    }
    const float s = 1.0f / SEQ;
    float4 m4 = make_float4(ax * s, ay * s, az * s, aw * s);
    *(float4*)(meanx + (size_t)n * DIN + dq) = m4;
}

// ---------------- q/k projection ----------------
__global__ __launch_bounds__(128) void qk_kernel(const float* __restrict__ meanx,
                                                 const float* __restrict__ Wq,
                                                 const float* __restrict__ bq,
                                                 const float* __restrict__ Wk,
                                                 const float* __restrict__ bk,
                                                 float* __restrict__ q,
                                                 float* __restrict__ k) {
    __shared__ float ms[8][DIN];
    int n0 = blockIdx.x * 8;
    int tid = threadIdx.x;
    for (int i = tid; i < 8 * DIN; i += 128) {
        int nn = n0 + (i >> 6);
        ms[i >> 6][i & 63] = (nn < NN) ? meanx[(size_t)nn * DIN + (i & 63)] : 0.f;
    }
    __syncthreads();
    int j = tid;
    float accq[8], acck[8];
    float bqv = bq[j], bkv = bk[j];
    #pragma unroll
    for (int r = 0; r < 8; ++r) { accq[r] = bqv; acck[r] = bkv; }
    for (int d = 0; d < DIN; ++d) {
        float wq = Wq[d * OCN + j], wk = Wk[d * OCN + j];
        #pragma unroll
        for (int r = 0; r < 8; ++r) {
            float mv = ms[r][d];
            accq[r] += mv * wq;
            acck[r] += mv * wk;
        }
    }
    const float qscale = 0.088388347648318447f;  // 1/sqrt(128)
    #pragma unroll
    for (int r = 0; r < 8; ++r) {
        int nn = n0 + r;
        if (nn < NN) {
            q[(size_t)nn * OCN + j] = accq[r] * qscale;
            k[(size_t)nn * OCN + j] = acck[r];
        }
    }
}

// ---------------- CSR build ----------------
__global__ __launch_bounds__(256) void hist_kernel(const int* __restrict__ dst,
                                                   int* __restrict__ cnt) {
    int e = blockIdx.x * 256 + threadIdx.x;
    if (e < NE) atomicAdd(&cnt[dst[e]], 1);
}

__global__ __launch_bounds__(1024) void scan_kernel(const int* __restrict__ cnt,
                                                    int* __restrict__ offs) {
    __shared__ int sums[1024], sums2[1024];
    int tid = threadIdx.x;
    int base = tid * 4;
    int v[4];
    #pragma unroll
    for (int i = 0; i < 4; ++i) v[i] = (base + i < NN) ? cnt[base + i] : 0;
    sums[tid] = v[0] + v[1] + v[2] + v[3];
    __syncthreads();
    int* a = sums;
    int* b2 = sums2;
    for (int off = 1; off < 1024; off <<= 1) {
        int val = a[tid] + ((tid >= off) ? a[tid - off] : 0);
        b2[tid] = val;
        __syncthreads();
        int* t = a; a = b2; b2 = t;
    }
    int prev = (tid > 0) ? a[tid - 1] : 0;
    int run = prev;
    #pragma unroll
    for (int i = 0; i < 4; ++i) {
        if (base + i <= NN) offs[base + i] = run;
        run += v[i];
    }
}

__global__ __launch_bounds__(256) void scatter_kernel(const int* __restrict__ src,
                                                      const int* __restrict__ dst,
                                                      const int* __restrict__ offs,
                                                      int* __restrict__ fill,
                                                      int* __restrict__ csr_src) {
    int e = blockIdx.x * 256 + threadIdx.x;
    if (e >= NE) return;
    int d0 = dst[e];
    int pos = offs[d0] + atomicAdd(&fill[d0], 1);
    csr_src[pos] = src[e];
}

// ---------------- per-edge attention weights (scores + segment softmax) ----------------
__global__ __launch_bounds__(256) void alpha_kernel(const float* __restrict__ q,
                                                    const float* __restrict__ k,
                                                    const int* __restrict__ offs,
                                                    const int* __restrict__ csr,
                                                    float* __restrict__ alpha) {
    __shared__ float qs[OCN];
    __shared__ float sc[GDEG];
    __shared__ int sidx[GDEG];
    int n = blockIdx.x;
    int start = offs[n];
    int deg = offs[n + 1] - start;
    if (deg > GDEG) deg = GDEG;
    int tid = threadIdx.x;
    if (tid < OCN) qs[tid] = q[(size_t)n * OCN + tid];
    for (int i = tid; i < deg; i += 256) sidx[i] = csr[start + i];
    __syncthreads();
    int lane = tid & 63;
    int wv = tid >> 6;
    for (int i = wv; i < deg; i += 4) {
        const float* kk = k + (size_t)sidx[i] * OCN;
        float p = kk[lane] * qs[lane] + kk[lane + 64] * qs[lane + 64];
        #pragma unroll
        for (int off = 32; off; off >>= 1) p += __shfl_down(p, off);
        if (lane == 0) sc[i] = p;
    }
    __syncthreads();
    float m = -1e30f;
    for (int i = 0; i < deg; ++i) m = fmaxf(m, sc[i]);
    __syncthreads();
    for (int i = tid; i < deg; i += 256) sc[i] = __expf(sc[i] - m);
    __syncthreads();
    float ssum = 0.f;
    for (int i = 0; i < deg; ++i) ssum += sc[i];
    float inv = (deg > 0) ? (1.0f / ssum) : 0.f;
    for (int i = tid; i < deg; i += 256) alpha[start + i] = sc[i] * inv;
}

// ---------------- t-chunked weighted gather, XCD-pinned chunks, 1 wave = 1 (n,chunk) ----------------
// bid = ch + 8*ng ; chunk ch pinned to XCD ch (per-XCD 3.4 MB xt slice L2-resident).
// Each wave: full deg loop, 2-deep software pipeline, register accumulate, direct store.
__global__ __launch_bounds__(256) void gather2_kernel(const u16* __restrict__ xt,
                                                      const float* __restrict__ alpha,
                                                      const int* __restrict__ offs,
                                                      const int* __restrict__ csr,
                                                      u16* __restrict__ yb) {
    int bid = blockIdx.x;
    int ch = bid & 7;
    int ng = bid >> 3;              // 0..827  (NN = 4*828)
    int wid = threadIdx.x >> 6;
    int lane = threadIdx.x & 63;
    int n = ng * 4 + wid;
    int t0 = ch * TCH;
    int b = n / CID, c = n - b * CID;
    int start = offs[n];
    int deg = offs[n + 1] - start;
    int t = lane >> 3;              // 0..7
    int dg = lane & 7;              // 8 d's (16B)
    const u16* xbase = xt + ((size_t)(t0 + t) * NN) * DIN + (dg << 3);

    float acc[8];
    #pragma unroll
    for (int j = 0; j < 8; ++j) acc[j] = 0.f;

    int s0 = 0; float a0 = 0.f;
    uint4 v0 = make_uint4(0, 0, 0, 0);
    if (deg > 0) {
        s0 = csr[start] << 6;
        a0 = alpha[start];
        v0 = *(const uint4*)(xbase + s0);
    }
    for (int i = 1; i < deg; ++i) {
        int s1 = csr[start + i] << 6;
        float a1 = alpha[start + i];
        uint4 v1 = *(const uint4*)(xbase + s1);
        acc[0] += a0 * bflo(v0.x); acc[1] += a0 * bfhi(v0.x);
        acc[2] += a0 * bflo(v0.y); acc[3] += a0 * bfhi(v0.y);
        acc[4] += a0 * bflo(v0.z); acc[5] += a0 * bfhi(v0.z);
        acc[6] += a0 * bflo(v0.w); acc[7] += a0 * bfhi(v0.w);
        a0 = a1; v0 = v1;
    }
    if (deg > 0) {
        acc[0] += a0 * bflo(v0.x); acc[1] += a0 * bfhi(v0.x);
        acc[2] += a0 * bflo(v0.y); acc[3] += a0 * bfhi(v0.y);
        acc[4] += a0 * bflo(v0.z); acc[5] += a0 * bfhi(v0.z);
        acc[6] += a0 * bflo(v0.w); acc[7] += a0 * bfhi(v0.w);
    }
    uint4 o;
    o.x = packbf(acc[0], acc[1]);
    o.y = packbf(acc[2], acc[3]);
    o.z = packbf(acc[4], acc[5]);
    o.w = packbf(acc[6], acc[7]);
    *(uint4*)(yb + ((size_t)b * SEQ + t0 + t) * ICD + c * DIN + (dg << 3)) = o;
}

// ---------------- conv weight -> MFMA B-fragment layout (bf16) ----------------
__global__ __launch_bounds__(256) void wprep_kernel(const float* __restrict__ cw,
                                                    u16* __restrict__ wf) {
    __shared__ float s_cw[128][100];  // 96 cols + pad
    int kstep = blockIdx.x;           // 0..415
    int ic0 = kstep * 32;
    int tid = threadIdx.x;
    {
        int oc = tid >> 1, hf = tid & 1;
        const float* src = cw + (size_t)oc * (ICD * KW) + (size_t)ic0 * 3 + hf * 48;
        #pragma unroll
        for (int u = 0; u < 48; ++u) {
            int col = hf * 48 + u;
            int ic = ic0 + col / 3;
            float v = 0.f;
            if (ic < ICD) v = src[u];
            s_cw[oc][col] = v;
        }
    }
    __syncthreads();
    #pragma unroll
    for (int r = 0; r < 6; ++r) {
        int f = tid + 256 * r;        // 0..1535
        int lane = f & 63;
        int nt = (f >> 6) & 7;
        int w = f >> 9;
        int row = nt * 16 + (lane & 15);
        int cb = 8 * (lane >> 4);
        uint4 o;
        u32 p[4];
        #pragma unroll
        for (int pj = 0; pj < 4; ++pj) {
            float v0 = s_cw[row][(cb + 2 * pj) * 3 + w];
            float v1 = s_cw[row][(cb + 2 * pj + 1) * 3 + w];
            p[pj] = packbf(v0, v1);
        }
        o.x = p[0]; o.y = p[1]; o.z = p[2]; o.w = p[3];
        size_t off = (((size_t)(kstep * 3 + w) * 8 + nt) * 64 + lane) * 8;
        *(uint4*)(wf + off) = o;
    }
}

// ---------------- conv1d as MFMA GEMM: 64t x 128oc per block, split-K(XCD-pinned) ----------------
__global__ __launch_bounds__(256) void conv_kernel(const u16* __restrict__ yb,
                                                   const u16* __restrict__ wf,
                                                   float* __restrict__ partial) {
    int bid = blockIdx.x;
    int xcd = bid & 7;
    int rest = bid >> 3;               // 0..63
    int khi = rest & 3;
    int b = rest >> 2;                 // 0..15
    int kc = xcd + (khi << 3);         // 0..31
    int tid = threadIdx.x;
    int lane = tid & 63;
    int wid = tid >> 6;
    int th = wid & 1;                  // t half: 0/32
    int nh = wid >> 1;                 // oc half: 0/64
    int lrow = lane & 15;
    int lq = lane >> 4;
    int tbase = th * 32;

    f32x4 acc[2][4];
    #pragma unroll
    for (int tt = 0; tt < 2; ++tt)
        #pragma unroll
        for (int n = 0; n < 4; ++n) acc[tt][n] = (f32x4){0.f, 0.f, 0.f, 0.f};

    const u16* ybA = yb + (size_t)b * SEQ * ICD + lq * 8;
    const u16* wfL = wf + (size_t)lane * 8 + ((size_t)nh * 4 * 64) * 8;
    int ks0 = kc * KSPC;

    bf16x8 aA[6], bA[12], aB[6], bB[12];

#define LOAD_AB(aR, bR, KS) do {                                              \
    int kstep_ = ks0 + (KS);                                                  \
    int ic0_ = kstep_ * 32;                                                   \
    _Pragma("unroll")                                                         \
    for (int tt_ = 0; tt_ < 2; ++tt_) {                                       \
        _Pragma("unroll")                                                     \
        for (int w_ = 0; w_ < 3; ++w_) {                                      \
            int ts_ = tbase + tt_ * 16 + lrow + w_ - 1;                       \
            bf16x8 av_ = {0, 0, 0, 0, 0, 0, 0, 0};                            \
            if ((unsigned)ts_ < SEQ)                                          \
                av_ = *(const bf16x8*)(ybA + (size_t)ts_ * ICD + ic0_);       \
            aR[tt_ * 3 + w_] = av_;                                           \
        }                                                                     \
    }                                                                         \
    const u16* wfp_ = wfL + (size_t)kstep_ * WFSTEP;                          \
    _Pragma("unroll")                                                         \
    for (int w_ = 0; w_ < 3; ++w_) {                                          \
        _Pragma("unroll")                                                     \
        for (int n_ = 0; n_ < 4; ++n_)                                        \
            bR[w_ * 4 + n_] = *(const bf16x8*)(wfp_ + (size_t)((w_ * 8 + n_) * 64) * 8); \
    }                                                                         \
} while (0)

#define COMPUTE(aR, bR) do {                                                  \
    _Pragma("unroll")                                                         \
    for (int w_ = 0; w_ < 3; ++w_) {                                          \
        _Pragma("unroll")                                                     \
        for (int tt_ = 0; tt_ < 2; ++tt_) {                                   \
            _Pragma("unroll")                                                 \
            for (int n_ = 0; n_ < 4; ++n_)                                    \
                acc[tt_][n_] = __builtin_amdgcn_mfma_f32_16x16x32_bf16(       \
                    aR[tt_ * 3 + w_], bR[w_ * 4 + n_], acc[tt_][n_], 0, 0, 0);\
        }                                                                     \
    }                                                                         \
} while (0)

    LOAD_AB(aA, bA, 0);
    #pragma unroll
    for (int ks = 0; ks < KSPC - 1; ks += 2) {
        LOAD_AB(aB, bB, ks + 1);
        COMPUTE(aA, bA);
        LOAD_AB(aA, bA, ks + 2);
        COMPUTE(aB, bB);
    }
    COMPUTE(aA, bA);   // ks = KSPC-1 (12)

    float* pp = partial + (size_t)kc * ((size_t)BZ * SEQ * OCN) + (size_t)b * SEQ * OCN + nh * 64;
    #pragma unroll
    for (int tt = 0; tt < 2; ++tt) {
        #pragma unroll
        for (int n = 0; n < 4; ++n) {
            #pragma unroll
            for (int r = 0; r < 4; ++r) {
                int t = tbase + tt * 16 + lq * 4 + r;
                pp[(size_t)t * OCN + n * 16 + lrow] = acc[tt][n][r];
            }
        }
    }
#undef LOAD_AB
#undef COMPUTE
}

// ---------------- split-K reduce (float4) ----------------
__global__ __launch_bounds__(256) void reduce_kernel(const float* __restrict__ partial,
                                                     float* __restrict__ out) {
    int i = (blockIdx.x * 256 + threadIdx.x) * 4;   // 131072 total
    float4 s = make_float4(0.f, 0.f, 0.f, 0.f);
    #pragma unroll
    for (int kc = 0; kc < NKC; ++kc) {
        float4 v = *(const float4*)(partial + (size_t)kc * 131072 + i);
        s.x += v.x; s.y += v.y; s.z += v.z; s.w += v.w;
    }
    *(float4*)(out + i) = s;
}

extern "C" void kernel_launch(void* const* d_in, const int* in_sizes, int n_in,
                              void* d_out, int out_size, void* d_ws, size_t ws_size,
                              hipStream_t stream) {
    const float* x   = (const float*)d_in[0];
    const float* Wq  = (const float*)d_in[1];
    const float* bqv = (const float*)d_in[2];
    const float* Wk  = (const float*)d_in[3];
    const float* bkv = (const float*)d_in[4];
    const float* cw  = (const float*)d_in[5];
    const int* esrc  = (const int*)d_in[6];
    const int* edst  = (const int*)d_in[7];

    char* ws = (char*)d_ws;
    size_t o = 0;
    auto alloc = [&](size_t bytes) {
        void* p = ws + o;
        o += (bytes + 255) & ~(size_t)255;
        return p;
    };
    u16*   xt    = (u16*)alloc(XTOT * 2);                 // 27.1 MB (aliased by partial after gather2)
    u16*   yb    = (u16*)alloc(XTOT * 2);                 // 27.1 MB
    u16*   wf    = (u16*)alloc((size_t)NKPAD * 3 * 8 * 64 * 8 * 2);  // 10.2 MB
    float* meanx = (float*)alloc((size_t)NN * DIN * 4);
    float* q     = (float*)alloc((size_t)NN * OCN * 4);
    float* k     = (float*)alloc((size_t)NN * OCN * 4);
    int*   cnt   = (int*)alloc(4096 * 4);
    int*   fill  = (int*)alloc(4096 * 4);
    int*   offs  = (int*)alloc(4352 * 4);
    int*   csr   = (int*)alloc((size_t)NE * 4);
    float* alpha = (float*)alloc((size_t)NE * 4);
    float* partial = (float*)xt;   // alias: xt dead after gather2; partial live conv->reduce (16.8 MB < 27.1 MB)

    hipMemsetAsync(cnt, 0, 4096 * 4, stream);
    hipMemsetAsync(fill, 0, 4096 * 4, stream);

    cvtmean_kernel<<<dim3(16, 13), dim3(256), 0, stream>>>(x, xt, meanx);
    qk_kernel<<<dim3(NN / 8), dim3(128), 0, stream>>>(meanx, Wq, bqv, Wk, bkv, q, k);
    hist_kernel<<<dim3((NE + 255) / 256), dim3(256), 0, stream>>>(edst, cnt);
    scan_kernel<<<dim3(1), dim3(1024), 0, stream>>>(cnt, offs);
    scatter_kernel<<<dim3((NE + 255) / 256), dim3(256), 0, stream>>>(esrc, edst, offs, fill, csr);
    wprep_kernel<<<dim3(NKPAD), dim3(256), 0, stream>>>(cw, wf);
    alpha_kernel<<<dim3(NN), dim3(256), 0, stream>>>(q, k, offs, csr, alpha);
    gather2_kernel<<<dim3((NN / 4) * NCHUNK), dim3(256), 0, stream>>>(xt, alpha, offs, csr, yb);
    conv_kernel<<<dim3(512), dim3(256), 0, stream>>>(yb, wf, partial);
    reduce_kernel<<<dim3(131072 / 4 / 256), dim3(256), 0, stream>>>(partial, (float*)d_out);
}

// Round 8
// 154.990 us; speedup vs baseline: 1.2158x; 1.0845x over previous
//
#include <hip/hip_runtime.h>
#include <hip/hip_bf16.h>
#include <math.h>

#define BZ 16
#define SEQ 64
#define CID 207
#define DIN 64
#define OCN 128
#define NN (BZ*CID)        // 3312
#define NE (NN*16)         // 52992
#define ICD (CID*DIN)      // 13248
#define KW 3
#define NKSTEP 414         // ICD/32
#define NKPAD 416          // padded to 32*13
#define NKC 32             // K-split chunks
#define KSPC 13            // ksteps per chunk
#define XTOT ((size_t)BZ*SEQ*ICD)   // 13565952
#define TCH 8              // t-chunk for gather
#define NCHUNK (SEQ/TCH)   // 8
#define GDEG 256           // alpha LDS cap (actual max deg ~45)
#define WFSTEP (3*8*64*8)  // wf elems per kstep = 12288

// fused3 block ranges
#define CVB 208            // cvtmean blocks (16*13)
#define SCB 207            // scatter blocks (NE/256)
#define WPB NKPAD          // wprep blocks

typedef __attribute__((ext_vector_type(8))) short bf16x8;
typedef __attribute__((ext_vector_type(4))) float f32x4;
typedef unsigned short u16;
typedef unsigned int u32;

__device__ __forceinline__ float bflo(u32 u) {
    u32 v = u << 16;
    return __builtin_bit_cast(float, v);
}
__device__ __forceinline__ float bfhi(u32 u) {
    u32 v = u & 0xFFFF0000u;
    return __builtin_bit_cast(float, v);
}
__device__ __forceinline__ u16 f2bf(float f) {
    __hip_bfloat16 h = __float2bfloat16(f);
    return __builtin_bit_cast(u16, h);
}
__device__ __forceinline__ u32 packbf(float f0, float f1) {
    return ((u32)f2bf(f1) << 16) | (u32)f2bf(f0);
}

// ---------------- LDS histogram + block scan (replaces memset+hist+scan) ----------------
__global__ __launch_bounds__(1024) void histscan_kernel(const int* __restrict__ edst,
                                                        int* __restrict__ offs,
                                                        int* __restrict__ fill) {
    __shared__ int hist[NN];
    __shared__ int sums[1024], sums2[1024];
    int tid = threadIdx.x;
    for (int i = tid; i < NN; i += 1024) hist[i] = 0;
    __syncthreads();
    for (int e = tid; e < NE; e += 1024) atomicAdd(&hist[edst[e]], 1);
    __syncthreads();
    int base = tid * 4;
    int v[4];
    #pragma unroll
    for (int i = 0; i < 4; ++i) v[i] = (base + i < NN) ? hist[base + i] : 0;
    sums[tid] = v[0] + v[1] + v[2] + v[3];
    __syncthreads();
    int* a = sums;
    int* b2 = sums2;
    for (int off = 1; off < 1024; off <<= 1) {
        int val = a[tid] + ((tid >= off) ? a[tid - off] : 0);
        b2[tid] = val;
        __syncthreads();
        int* t = a; a = b2; b2 = t;
    }
    int prev = (tid > 0) ? a[tid - 1] : 0;
    int run = prev;
    #pragma unroll
    for (int i = 0; i < 4; ++i) {
        if (base + i <= NN) {
            offs[base + i] = run;
            if (base + i < NN) fill[base + i] = run;
        }
        run += v[i];
    }
}

// ---------------- fused: cvtmean (0..207) | scatter (208..414) | wprep (415..830) ----------------
__global__ __launch_bounds__(256) void fused3_kernel(const float* __restrict__ x,
                                                     u16* __restrict__ xt,
                                                     float* __restrict__ meanx,
                                                     const int* __restrict__ esrc,
                                                     int* __restrict__ fill,
                                                     int* __restrict__ csr,
                                                     const int* __restrict__ edst,
                                                     const float* __restrict__ cw,
                                                     u16* __restrict__ wf) {
    __shared__ float s_cw[128][100];  // wprep scratch (51.2 KB, allocated for all branches)
    int bid = blockIdx.x;
    int tid = threadIdx.x;
    if (bid < CVB) {
        // ---- cvtmean: x -> bf16 transpose xt[t][n][d] + mean over t ----
        int bb = bid / 13;
        int cg = bid - bb * 13;
        int cl = tid >> 4;
        int dq = (tid & 15) << 2;
        int c = cg * 16 + cl;
        if (c >= CID) return;
        int n = bb * CID + c;
        const float* px = x + (size_t)bb * SEQ * ICD + (size_t)c * DIN + dq;
        u16* pxt = xt + (size_t)n * DIN + dq;
        float ax = 0.f, ay = 0.f, az = 0.f, aw = 0.f;
        #pragma unroll 4
        for (int t = 0; t < SEQ; ++t) {
            float4 v = *(const float4*)(px + (size_t)t * ICD);
            ax += v.x; ay += v.y; az += v.z; aw += v.w;
            uint2 w2;
            w2.x = packbf(v.x, v.y);
            w2.y = packbf(v.z, v.w);
            *(uint2*)(pxt + (size_t)t * NN * DIN) = w2;
        }
        const float s = 1.0f / SEQ;
        float4 m4 = make_float4(ax * s, ay * s, az * s, aw * s);
        *(float4*)(meanx + (size_t)n * DIN + dq) = m4;
    } else if (bid < CVB + SCB) {
        // ---- scatter: CSR fill (fill pre-initialized to offs by histscan) ----
        int e = (bid - CVB) * 256 + tid;   // exactly NE
        int d0 = edst[e];
        int pos = atomicAdd(&fill[d0], 1);
        csr[pos] = esrc[e];
    } else {
        // ---- wprep: conv weight -> MFMA B-fragment layout ----
        int kstep = bid - (CVB + SCB);    // 0..415
        int ic0 = kstep * 32;
        {
            int oc = tid >> 1, hf = tid & 1;
            const float* src = cw + (size_t)oc * (ICD * KW) + (size_t)ic0 * 3 + hf * 48;
            #pragma unroll
            for (int u = 0; u < 48; ++u) {
                int col = hf * 48 + u;
                int ic = ic0 + col / 3;
                float v = 0.f;
                if (ic < ICD) v = src[u];
                s_cw[oc][col] = v;
            }
        }
        __syncthreads();
        #pragma unroll
        for (int r = 0; r < 6; ++r) {
            int f = tid + 256 * r;        // 0..1535
            int lane = f & 63;
            int nt = (f >> 6) & 7;
            int w = f >> 9;
            int row = nt * 16 + (lane & 15);
            int cb = 8 * (lane >> 4);
            uint4 o;
            u32 p[4];
            #pragma unroll
            for (int pj = 0; pj < 4; ++pj) {
                float v0 = s_cw[row][(cb + 2 * pj) * 3 + w];
                float v1 = s_cw[row][(cb + 2 * pj + 1) * 3 + w];
                p[pj] = packbf(v0, v1);
            }
            o.x = p[0]; o.y = p[1]; o.z = p[2]; o.w = p[3];
            size_t off = (((size_t)(kstep * 3 + w) * 8 + nt) * 64 + lane) * 8;
            *(uint4*)(wf + off) = o;
        }
    }
}

// ---------------- q/k projection: 16 nodes per 256-thread block ----------------
__global__ __launch_bounds__(256) void qk_kernel(const float* __restrict__ meanx,
                                                 const float* __restrict__ Wq,
                                                 const float* __restrict__ bq,
                                                 const float* __restrict__ Wk,
                                                 const float* __restrict__ bk,
                                                 float* __restrict__ q,
                                                 float* __restrict__ k) {
    __shared__ float ms[16][DIN];
    int n0 = blockIdx.x * 16;
    int tid = threadIdx.x;
    for (int i = tid; i < 16 * DIN; i += 256)
        ms[i >> 6][i & 63] = meanx[(size_t)(n0 + (i >> 6)) * DIN + (i & 63)];
    __syncthreads();
    int j = tid & 127;
    int g = tid >> 7;                 // node group 0/1 (8 nodes each)
    float accq[8], acck[8];
    float bqv = bq[j], bkv = bk[j];
    #pragma unroll
    for (int r = 0; r < 8; ++r) { accq[r] = bqv; acck[r] = bkv; }
    for (int d = 0; d < DIN; ++d) {
        float wq = Wq[d * OCN + j], wk = Wk[d * OCN + j];
        #pragma unroll
        for (int r = 0; r < 8; ++r) {
            float mv = ms[g * 8 + r][d];
            accq[r] += mv * wq;
            acck[r] += mv * wk;
        }
    }
    const float qscale = 0.088388347648318447f;  // 1/sqrt(128)
    #pragma unroll
    for (int r = 0; r < 8; ++r) {
        int nn = n0 + g * 8 + r;
        q[(size_t)nn * OCN + j] = accq[r] * qscale;
        k[(size_t)nn * OCN + j] = acck[r];
    }
}

// ---------------- per-edge attention weights (scores + segment softmax) ----------------
__global__ __launch_bounds__(256) void alpha_kernel(const float* __restrict__ q,
                                                    const float* __restrict__ k,
                                                    const int* __restrict__ offs,
                                                    const int* __restrict__ csr,
                                                    float* __restrict__ alpha) {
    __shared__ float qs[OCN];
    __shared__ float sc[GDEG];
    __shared__ int sidx[GDEG];
    int n = blockIdx.x;
    int start = offs[n];
    int deg = offs[n + 1] - start;
    if (deg > GDEG) deg = GDEG;
    int tid = threadIdx.x;
    if (tid < OCN) qs[tid] = q[(size_t)n * OCN + tid];
    for (int i = tid; i < deg; i += 256) sidx[i] = csr[start + i];
    __syncthreads();
    int lane = tid & 63;
    int wv = tid >> 6;
    for (int i = wv; i < deg; i += 4) {
        const float* kk = k + (size_t)sidx[i] * OCN;
        float p = kk[lane] * qs[lane] + kk[lane + 64] * qs[lane + 64];
        #pragma unroll
        for (int off = 32; off; off >>= 1) p += __shfl_down(p, off);
        if (lane == 0) sc[i] = p;
    }
    __syncthreads();
    float m = -1e30f;
    for (int i = 0; i < deg; ++i) m = fmaxf(m, sc[i]);
    __syncthreads();
    for (int i = tid; i < deg; i += 256) sc[i] = __expf(sc[i] - m);
    __syncthreads();
    float ssum = 0.f;
    for (int i = 0; i < deg; ++i) ssum += sc[i];
    float inv = (deg > 0) ? (1.0f / ssum) : 0.f;
    for (int i = tid; i < deg; i += 256) alpha[start + i] = sc[i] * inv;
}

// ---------------- t-chunked weighted gather, XCD-pinned, shfl-broadcast edges ----------------
// bid = ch + 8*ng ; 1 wave = 1 (n,chunk). Edge list (deg<=64 in this data) preloaded
// one-per-lane and broadcast via __shfl -> inner loop has only the xt uint4 load.
__global__ __launch_bounds__(256) void gather2_kernel(const u16* __restrict__ xt,
                                                      const float* __restrict__ alpha,
                                                      const int* __restrict__ offs,
                                                      const int* __restrict__ csr,
                                                      u16* __restrict__ yb) {
    int bid = blockIdx.x;
    int ch = bid & 7;
    int ng = bid >> 3;              // 0..827
    int wid = threadIdx.x >> 6;
    int lane = threadIdx.x & 63;
    int n = ng * 4 + wid;
    int t0 = ch * TCH;
    int b = n / CID, c = n - b * CID;
    int start = offs[n];
    int deg = offs[n + 1] - start;
    int t = lane >> 3;              // 0..7
    int dg = lane & 7;              // 8 d's (16B)
    const u16* xbase = xt + ((size_t)(t0 + t) * NN) * DIN + (dg << 3);

    int sAll = 0; float aAll = 0.f;
    if (lane < deg) {
        sAll = csr[start + lane] << 6;
        aAll = alpha[start + lane];
    }
    int dmax = (deg <= 64) ? deg : 64;

    float acc[8];
    #pragma unroll
    for (int j = 0; j < 8; ++j) acc[j] = 0.f;

    float a0 = 0.f;
    uint4 v0 = make_uint4(0, 0, 0, 0);
    if (dmax > 0) {
        int s0 = __shfl(sAll, 0);
        a0 = __shfl(aAll, 0);
        v0 = *(const uint4*)(xbase + s0);
    }
    for (int i = 1; i < dmax; ++i) {
        int s1 = __shfl(sAll, i);
        float a1 = __shfl(aAll, i);
        uint4 v1 = *(const uint4*)(xbase + s1);
        acc[0] += a0 * bflo(v0.x); acc[1] += a0 * bfhi(v0.x);
        acc[2] += a0 * bflo(v0.y); acc[3] += a0 * bfhi(v0.y);
        acc[4] += a0 * bflo(v0.z); acc[5] += a0 * bfhi(v0.z);
        acc[6] += a0 * bflo(v0.w); acc[7] += a0 * bfhi(v0.w);
        a0 = a1; v0 = v1;
    }
    if (dmax > 0) {
        acc[0] += a0 * bflo(v0.x); acc[1] += a0 * bfhi(v0.x);
        acc[2] += a0 * bflo(v0.y); acc[3] += a0 * bfhi(v0.y);
        acc[4] += a0 * bflo(v0.z); acc[5] += a0 * bfhi(v0.z);
        acc[6] += a0 * bflo(v0.w); acc[7] += a0 * bfhi(v0.w);
    }
    for (int i = 64; i < deg; ++i) {   // safety tail (not hit for this data)
        int s = csr[start + i] << 6;
        float a = alpha[start + i];
        uint4 v = *(const uint4*)(xbase + s);
        acc[0] += a * bflo(v.x); acc[1] += a * bfhi(v.x);
        acc[2] += a * bflo(v.y); acc[3] += a * bfhi(v.y);
        acc[4] += a * bflo(v.z); acc[5] += a * bfhi(v.z);
        acc[6] += a * bflo(v.w); acc[7] += a * bfhi(v.w);
    }
    uint4 o;
    o.x = packbf(acc[0], acc[1]);
    o.y = packbf(acc[2], acc[3]);
    o.z = packbf(acc[4], acc[5]);
    o.w = packbf(acc[6], acc[7]);
    *(uint4*)(yb + ((size_t)b * SEQ + t0 + t) * ICD + c * DIN + (dg << 3)) = o;
}

// ---------------- conv1d as MFMA GEMM: 64t x 128oc per block, split-K(XCD-pinned) ----------------
__global__ __launch_bounds__(256) void conv_kernel(const u16* __restrict__ yb,
                                                   const u16* __restrict__ wf,
                                                   float* __restrict__ partial) {
    int bid = blockIdx.x;
    int xcd = bid & 7;
    int rest = bid >> 3;               // 0..63
    int khi = rest & 3;
    int b = rest >> 2;                 // 0..15
    int kc = xcd + (khi << 3);         // 0..31
    int tid = threadIdx.x;
    int lane = tid & 63;
    int wid = tid >> 6;
    int th = wid & 1;                  // t half: 0/32
    int nh = wid >> 1;                 // oc half: 0/64
    int lrow = lane & 15;
    int lq = lane >> 4;
    int tbase = th * 32;

    f32x4 acc[2][4];
    #pragma unroll
    for (int tt = 0; tt < 2; ++tt)
        #pragma unroll
        for (int n = 0; n < 4; ++n) acc[tt][n] = (f32x4){0.f, 0.f, 0.f, 0.f};

    const u16* ybA = yb + (size_t)b * SEQ * ICD + lq * 8;
    const u16* wfL = wf + (size_t)lane * 8 + ((size_t)nh * 4 * 64) * 8;
    int ks0 = kc * KSPC;

    bf16x8 aA[6], bA[12], aB[6], bB[12];

#define LOAD_AB(aR, bR, KS) do {                                              \
    int kstep_ = ks0 + (KS);                                                  \
    int ic0_ = kstep_ * 32;                                                   \
    _Pragma("unroll")                                                         \
    for (int tt_ = 0; tt_ < 2; ++tt_) {                                       \
        _Pragma("unroll")                                                     \
        for (int w_ = 0; w_ < 3; ++w_) {                                      \
            int ts_ = tbase + tt_ * 16 + lrow + w_ - 1;                       \
            bf16x8 av_ = {0, 0, 0, 0, 0, 0, 0, 0};                            \
            if ((unsigned)ts_ < SEQ)                                          \
                av_ = *(const bf16x8*)(ybA + (size_t)ts_ * ICD + ic0_);       \
            aR[tt_ * 3 + w_] = av_;                                           \
        }                                                                     \
    }                                                                         \
    const u16* wfp_ = wfL + (size_t)kstep_ * WFSTEP;                          \
    _Pragma("unroll")                                                         \
    for (int w_ = 0; w_ < 3; ++w_) {                                          \
        _Pragma("unroll")                                                     \
        for (int n_ = 0; n_ < 4; ++n_)                                        \
            bR[w_ * 4 + n_] = *(const bf16x8*)(wfp_ + (size_t)((w_ * 8 + n_) * 64) * 8); \
    }                                                                         \
} while (0)

#define COMPUTE(aR, bR) do {                                                  \
    _Pragma("unroll")                                                         \
    for (int w_ = 0; w_ < 3; ++w_) {                                          \
        _Pragma("unroll")                                                     \
        for (int tt_ = 0; tt_ < 2; ++tt_) {                                   \
            _Pragma("unroll")                                                 \
            for (int n_ = 0; n_ < 4; ++n_)                                    \
                acc[tt_][n_] = __builtin_amdgcn_mfma_f32_16x16x32_bf16(       \
                    aR[tt_ * 3 + w_], bR[w_ * 4 + n_], acc[tt_][n_], 0, 0, 0);\
        }                                                                     \
    }                                                                         \
} while (0)

    LOAD_AB(aA, bA, 0);
    #pragma unroll
    for (int ks = 0; ks < KSPC - 1; ks += 2) {
        LOAD_AB(aB, bB, ks + 1);
        COMPUTE(aA, bA);
        LOAD_AB(aA, bA, ks + 2);
        COMPUTE(aB, bB);
    }
    COMPUTE(aA, bA);   // ks = KSPC-1 (12)

    float* pp = partial + (size_t)kc * ((size_t)BZ * SEQ * OCN) + (size_t)b * SEQ * OCN + nh * 64;
    #pragma unroll
    for (int tt = 0; tt < 2; ++tt) {
        #pragma unroll
        for (int n = 0; n < 4; ++n) {
            #pragma unroll
            for (int r = 0; r < 4; ++r) {
                int t = tbase + tt * 16 + lq * 4 + r;
                pp[(size_t)t * OCN + n * 16 + lrow] = acc[tt][n][r];
            }
        }
    }
#undef LOAD_AB
#undef COMPUTE
}

// ---------------- split-K reduce (float4) ----------------
__global__ __launch_bounds__(256) void reduce_kernel(const float* __restrict__ partial,
                                                     float* __restrict__ out) {
    int i = (blockIdx.x * 256 + threadIdx.x) * 4;   // 131072 total
    float4 s = make_float4(0.f, 0.f, 0.f, 0.f);
    #pragma unroll
    for (int kc = 0; kc < NKC; ++kc) {
        float4 v = *(const float4*)(partial + (size_t)kc * 131072 + i);
        s.x += v.x; s.y += v.y; s.z += v.z; s.w += v.w;
    }
    *(float4*)(out + i) = s;
}

extern "C" void kernel_launch(void* const* d_in, const int* in_sizes, int n_in,
                              void* d_out, int out_size, void* d_ws, size_t ws_size,
                              hipStream_t stream) {
    const float* x   = (const float*)d_in[0];
    const float* Wq  = (const float*)d_in[1];
    const float* bqv = (const float*)d_in[2];
    const float* Wk  = (const float*)d_in[3];
    const float* bkv = (const float*)d_in[4];
    const float* cw  = (const float*)d_in[5];
    const int* esrc  = (const int*)d_in[6];
    const int* edst  = (const int*)d_in[7];

    char* ws = (char*)d_ws;
    size_t o = 0;
    auto alloc = [&](size_t bytes) {
        void* p = ws + o;
        o += (bytes + 255) & ~(size_t)255;
        return p;
    };
    u16*   xt    = (u16*)alloc(XTOT * 2);                 // 27.1 MB (aliased by partial after gather2)
    u16*   yb    = (u16*)alloc(XTOT * 2);                 // 27.1 MB
    u16*   wf    = (u16*)alloc((size_t)NKPAD * 3 * 8 * 64 * 8 * 2);  // 10.2 MB
    float* meanx = (float*)alloc((size_t)NN * DIN * 4);
    float* q     = (float*)alloc((size_t)NN * OCN * 4);
    float* k     = (float*)alloc((size_t)NN * OCN * 4);
    int*   fill  = (int*)alloc(4096 * 4);
    int*   offs  = (int*)alloc(4352 * 4);
    int*   csr   = (int*)alloc((size_t)NE * 4);
    float* alpha = (float*)alloc((size_t)NE * 4);
    float* partial = (float*)xt;   // alias: xt dead after gather2; partial live conv->reduce

    histscan_kernel<<<dim3(1), dim3(1024), 0, stream>>>(edst, offs, fill);
    fused3_kernel<<<dim3(CVB + SCB + WPB), dim3(256), 0, stream>>>(x, xt, meanx, esrc, fill, csr, edst, cw, wf);
    qk_kernel<<<dim3(NN / 16), dim3(256), 0, stream>>>(meanx, Wq, bqv, Wk, bkv, q, k);
    alpha_kernel<<<dim3(NN), dim3(256), 0, stream>>>(q, k, offs, csr, alpha);
    gather2_kernel<<<dim3((NN / 4) * NCHUNK), dim3(256), 0, stream>>>(xt, alpha, offs, csr, yb);
    conv_kernel<<<dim3(512), dim3(256), 0, stream>>>(yb, wf, partial);
    reduce_kernel<<<dim3(131072 / 4 / 256), dim3(256), 0, stream>>>(partial, (float*)d_out);
}

// Round 9
// 133.975 us; speedup vs baseline: 1.4066x; 1.1569x over previous
//
#include <hip/hip_runtime.h>
#include <hip/hip_bf16.h>
#include <math.h>

#define BZ 16
#define SEQ 64
#define CID 207
#define DIN 64
#define OCN 128
#define NN (BZ*CID)        // 3312
#define NE (NN*16)         // 52992
#define ICD (CID*DIN)      // 13248
#define KW 3
#define NKSTEP 414         // ICD/32
#define NKPAD 416          // padded to 32*13
#define NKC 32             // K-split chunks
#define KSPC 13            // ksteps per chunk
#define XTOT ((size_t)BZ*SEQ*ICD)   // 13565952
#define TCH 8              // t-chunk for gather
#define NCHUNK (SEQ/TCH)   // 8
#define GDEG 256           // alpha LDS cap (actual max deg ~45)
#define WFSTEP (3*8*64*8)  // wf elems per kstep = 12288

// fused3 block ranges: cvtmean (16*13*4) | scatter (NE/256) | wprep (NKPAD*4)
#define CVB 832
#define SCB 207
#define WPB (NKPAD*4)

typedef __attribute__((ext_vector_type(8))) short bf16x8;
typedef __attribute__((ext_vector_type(4))) float f32x4;
typedef unsigned short u16;
typedef unsigned int u32;

__device__ __forceinline__ float bflo(u32 u) {
    u32 v = u << 16;
    return __builtin_bit_cast(float, v);
}
__device__ __forceinline__ float bfhi(u32 u) {
    u32 v = u & 0xFFFF0000u;
    return __builtin_bit_cast(float, v);
}
__device__ __forceinline__ u16 f2bf(float f) {
    __hip_bfloat16 h = __float2bfloat16(f);
    return __builtin_bit_cast(u16, h);
}
__device__ __forceinline__ u32 packbf(float f0, float f1) {
    return ((u32)f2bf(f1) << 16) | (u32)f2bf(f0);
}

// ---------------- LDS histogram + block scan ----------------
__global__ __launch_bounds__(1024) void histscan_kernel(const int* __restrict__ edst,
                                                        int* __restrict__ offs,
                                                        int* __restrict__ fill) {
    __shared__ int hist[NN];
    __shared__ int sums[1024], sums2[1024];
    int tid = threadIdx.x;
    for (int i = tid; i < NN; i += 1024) hist[i] = 0;
    __syncthreads();
    for (int e = tid; e < NE; e += 1024) atomicAdd(&hist[edst[e]], 1);
    __syncthreads();
    int base = tid * 4;
    int v[4];
    #pragma unroll
    for (int i = 0; i < 4; ++i) v[i] = (base + i < NN) ? hist[base + i] : 0;
    sums[tid] = v[0] + v[1] + v[2] + v[3];
    __syncthreads();
    int* a = sums;
    int* b2 = sums2;
    for (int off = 1; off < 1024; off <<= 1) {
        int val = a[tid] + ((tid >= off) ? a[tid - off] : 0);
        b2[tid] = val;
        __syncthreads();
        int* t = a; a = b2; b2 = t;
    }
    int prev = (tid > 0) ? a[tid - 1] : 0;
    int run = prev;
    #pragma unroll
    for (int i = 0; i < 4; ++i) {
        if (base + i <= NN) {
            offs[base + i] = run;
            if (base + i < NN) fill[base + i] = run;
        }
        run += v[i];
    }
}

// ---------------- fused: cvtmean(t-split x4) | scatter | wprep(32-oc) ----------------
__global__ __launch_bounds__(256) void fused3_kernel(const float* __restrict__ x,
                                                     u16* __restrict__ xt,
                                                     float* __restrict__ meanp,
                                                     const int* __restrict__ esrc,
                                                     int* __restrict__ fill,
                                                     int* __restrict__ csr,
                                                     const int* __restrict__ edst,
                                                     const float* __restrict__ cw,
                                                     u16* __restrict__ wf) {
    __shared__ float s_cw[32][100];   // wprep scratch, 12.8 KB
    int bid = blockIdx.x;
    int tid = threadIdx.x;
    if (bid < CVB) {
        // ---- cvtmean: 16 t's per block; partial sum -> meanp[tq] ----
        int bb = bid / 52;
        int rem = bid - bb * 52;
        int cg = rem >> 2;            // 0..12
        int tq = rem & 3;             // t-quarter
        int cl = tid >> 4;
        int dq = (tid & 15) << 2;
        int c = cg * 16 + cl;
        if (c >= CID) return;
        int n = bb * CID + c;
        const float* px = x + (size_t)bb * SEQ * ICD + (size_t)(tq * 16) * ICD + (size_t)c * DIN + dq;
        u16* pxt = xt + ((size_t)(tq * 16) * NN + n) * DIN + dq;
        float ax = 0.f, ay = 0.f, az = 0.f, aw = 0.f;
        #pragma unroll 4
        for (int t = 0; t < 16; ++t) {
            float4 v = *(const float4*)(px + (size_t)t * ICD);
            ax += v.x; ay += v.y; az += v.z; aw += v.w;
            uint2 w2;
            w2.x = packbf(v.x, v.y);
            w2.y = packbf(v.z, v.w);
            *(uint2*)(pxt + (size_t)t * NN * DIN) = w2;
        }
        *(float4*)(meanp + ((size_t)tq * NN + n) * DIN + dq) = make_float4(ax, ay, az, aw);
    } else if (bid < CVB + SCB) {
        // ---- scatter: CSR fill (fill pre-initialized to offs by histscan) ----
        int e = (bid - CVB) * 256 + tid;   // exactly NE
        int d0 = edst[e];
        int pos = atomicAdd(&fill[d0], 1);
        csr[pos] = esrc[e];
    } else {
        // ---- wprep: conv weight -> MFMA B-fragment layout, 32 oc (2 nt) per block ----
        int wkb = bid - (CVB + SCB);
        int kstep = wkb >> 2;             // 0..415
        int p = wkb & 3;                  // oc quarter
        int ic0 = kstep * 32;
        int col0 = ic0 * 3;               // flat col base in cw[oc][ICD*3]
        {
            int oc_l = tid >> 3;          // 0..31
            int seg = tid & 7;            // 12 cols each
            const float* src = cw + (size_t)(p * 32 + oc_l) * (ICD * KW) + col0 + seg * 12;
            #pragma unroll
            for (int u = 0; u < 12; ++u) {
                int col = seg * 12 + u;
                float v = (col0 + col < ICD * 3) ? src[u] : 0.f;
                s_cw[oc_l][col] = v;
            }
        }
        __syncthreads();
        #pragma unroll
        for (int r = 0; r < 2; ++r) {
            int f = tid + 256 * r;        // 0..511, use 0..383
            if (f < 384) {
                int lane = f & 63;
                int g = f >> 6;           // 0..5
                int ntl = g & 1;
                int w = g >> 1;
                int nt = p * 2 + ntl;
                int row = ntl * 16 + (lane & 15);
                int cb = 8 * (lane >> 4);
                uint4 o;
                u32 pk[4];
                #pragma unroll
                for (int pj = 0; pj < 4; ++pj) {
                    float v0 = s_cw[row][(cb + 2 * pj) * 3 + w];
                    float v1 = s_cw[row][(cb + 2 * pj + 1) * 3 + w];
                    pk[pj] = packbf(v0, v1);
                }
                o.x = pk[0]; o.y = pk[1]; o.z = pk[2]; o.w = pk[3];
                size_t off = (((size_t)(kstep * 3 + w) * 8 + nt) * 64 + lane) * 8;
                *(uint4*)(wf + off) = o;
            }
        }
    }
}

// ---------------- q/k projection: 16 nodes per 256-thread block; sums meanp[0..3] ----------------
__global__ __launch_bounds__(256) void qk_kernel(const float* __restrict__ meanp,
                                                 const float* __restrict__ Wq,
                                                 const float* __restrict__ bq,
                                                 const float* __restrict__ Wk,
                                                 const float* __restrict__ bk,
                                                 float* __restrict__ q,
                                                 float* __restrict__ k) {
    __shared__ float ms[16][DIN];
    int n0 = blockIdx.x * 16;
    int tid = threadIdx.x;
    const size_t PS = (size_t)NN * DIN;
    for (int i = tid; i < 16 * DIN; i += 256) {
        size_t off = (size_t)(n0 + (i >> 6)) * DIN + (i & 63);
        float s = meanp[off] + meanp[PS + off] + meanp[2 * PS + off] + meanp[3 * PS + off];
        ms[i >> 6][i & 63] = s * (1.0f / SEQ);
    }
    __syncthreads();
    int j = tid & 127;
    int g = tid >> 7;                 // node group 0/1 (8 nodes each)
    float accq[8], acck[8];
    float bqv = bq[j], bkv = bk[j];
    #pragma unroll
    for (int r = 0; r < 8; ++r) { accq[r] = bqv; acck[r] = bkv; }
    for (int d = 0; d < DIN; ++d) {
        float wq = Wq[d * OCN + j], wk = Wk[d * OCN + j];
        #pragma unroll
        for (int r = 0; r < 8; ++r) {
            float mv = ms[g * 8 + r][d];
            accq[r] += mv * wq;
            acck[r] += mv * wk;
        }
    }
    const float qscale = 0.088388347648318447f;  // 1/sqrt(128)
    #pragma unroll
    for (int r = 0; r < 8; ++r) {
        int nn = n0 + g * 8 + r;
        q[(size_t)nn * OCN + j] = accq[r] * qscale;
        k[(size_t)nn * OCN + j] = acck[r];
    }
}

// ---------------- per-edge attention weights (scores + segment softmax) ----------------
__global__ __launch_bounds__(256) void alpha_kernel(const float* __restrict__ q,
                                                    const float* __restrict__ k,
                                                    const int* __restrict__ offs,
                                                    const int* __restrict__ csr,
                                                    float* __restrict__ alpha) {
    __shared__ float qs[OCN];
    __shared__ float sc[GDEG];
    __shared__ int sidx[GDEG];
    int n = blockIdx.x;
    int start = offs[n];
    int deg = offs[n + 1] - start;
    if (deg > GDEG) deg = GDEG;
    int tid = threadIdx.x;
    if (tid < OCN) qs[tid] = q[(size_t)n * OCN + tid];
    for (int i = tid; i < deg; i += 256) sidx[i] = csr[start + i];
    __syncthreads();
    int lane = tid & 63;
    int wv = tid >> 6;
    for (int i = wv; i < deg; i += 4) {
        const float* kk = k + (size_t)sidx[i] * OCN;
        float p = kk[lane] * qs[lane] + kk[lane + 64] * qs[lane + 64];
        #pragma unroll
        for (int off = 32; off; off >>= 1) p += __shfl_down(p, off);
        if (lane == 0) sc[i] = p;
    }
    __syncthreads();
    float m = -1e30f;
    for (int i = 0; i < deg; ++i) m = fmaxf(m, sc[i]);
    __syncthreads();
    for (int i = tid; i < deg; i += 256) sc[i] = __expf(sc[i] - m);
    __syncthreads();
    float ssum = 0.f;
    for (int i = 0; i < deg; ++i) ssum += sc[i];
    float inv = (deg > 0) ? (1.0f / ssum) : 0.f;
    for (int i = tid; i < deg; i += 256) alpha[start + i] = sc[i] * inv;
}

// ---------------- t-chunked weighted gather, XCD-pinned, shfl-broadcast edges ----------------
__global__ __launch_bounds__(256) void gather2_kernel(const u16* __restrict__ xt,
                                                      const float* __restrict__ alpha,
                                                      const int* __restrict__ offs,
                                                      const int* __restrict__ csr,
                                                      u16* __restrict__ yb) {
    int bid = blockIdx.x;
    int ch = bid & 7;
    int ng = bid >> 3;              // 0..827
    int wid = threadIdx.x >> 6;
    int lane = threadIdx.x & 63;
    int n = ng * 4 + wid;
    int t0 = ch * TCH;
    int b = n / CID, c = n - b * CID;
    int start = offs[n];
    int deg = offs[n + 1] - start;
    int t = lane >> 3;              // 0..7
    int dg = lane & 7;              // 8 d's (16B)
    const u16* xbase = xt + ((size_t)(t0 + t) * NN) * DIN + (dg << 3);

    int sAll = 0; float aAll = 0.f;
    if (lane < deg) {
        sAll = csr[start + lane] << 6;
        aAll = alpha[start + lane];
    }
    int dmax = (deg <= 64) ? deg : 64;

    float acc[8];
    #pragma unroll
    for (int j = 0; j < 8; ++j) acc[j] = 0.f;

    float a0 = 0.f;
    uint4 v0 = make_uint4(0, 0, 0, 0);
    if (dmax > 0) {
        int s0 = __shfl(sAll, 0);
        a0 = __shfl(aAll, 0);
        v0 = *(const uint4*)(xbase + s0);
    }
    for (int i = 1; i < dmax; ++i) {
        int s1 = __shfl(sAll, i);
        float a1 = __shfl(aAll, i);
        uint4 v1 = *(const uint4*)(xbase + s1);
        acc[0] += a0 * bflo(v0.x); acc[1] += a0 * bfhi(v0.x);
        acc[2] += a0 * bflo(v0.y); acc[3] += a0 * bfhi(v0.y);
        acc[4] += a0 * bflo(v0.z); acc[5] += a0 * bfhi(v0.z);
        acc[6] += a0 * bflo(v0.w); acc[7] += a0 * bfhi(v0.w);
        a0 = a1; v0 = v1;
    }
    if (dmax > 0) {
        acc[0] += a0 * bflo(v0.x); acc[1] += a0 * bfhi(v0.x);
        acc[2] += a0 * bflo(v0.y); acc[3] += a0 * bfhi(v0.y);
        acc[4] += a0 * bflo(v0.z); acc[5] += a0 * bfhi(v0.z);
        acc[6] += a0 * bflo(v0.w); acc[7] += a0 * bfhi(v0.w);
    }
    for (int i = 64; i < deg; ++i) {   // safety tail (not hit for this data)
        int s = csr[start + i] << 6;
        float a = alpha[start + i];
        uint4 v = *(const uint4*)(xbase + s);
        acc[0] += a * bflo(v.x); acc[1] += a * bfhi(v.x);
        acc[2] += a * bflo(v.y); acc[3] += a * bfhi(v.y);
        acc[4] += a * bflo(v.z); acc[5] += a * bfhi(v.z);
        acc[6] += a * bflo(v.w); acc[7] += a * bfhi(v.w);
    }
    uint4 o;
    o.x = packbf(acc[0], acc[1]);
    o.y = packbf(acc[2], acc[3]);
    o.z = packbf(acc[4], acc[5]);
    o.w = packbf(acc[6], acc[7]);
    *(uint4*)(yb + ((size_t)b * SEQ + t0 + t) * ICD + c * DIN + (dg << 3)) = o;
}

// ---------------- conv1d as MFMA GEMM: 64t x 128oc per block, split-K(XCD-pinned) ----------------
__global__ __launch_bounds__(256) void conv_kernel(const u16* __restrict__ yb,
                                                   const u16* __restrict__ wf,
                                                   float* __restrict__ partial) {
    int bid = blockIdx.x;
    int xcd = bid & 7;
    int rest = bid >> 3;               // 0..63
    int khi = rest & 3;
    int b = rest >> 2;                 // 0..15
    int kc = xcd + (khi << 3);         // 0..31
    int tid = threadIdx.x;
    int lane = tid & 63;
    int wid = tid >> 6;
    int th = wid & 1;                  // t half: 0/32
    int nh = wid >> 1;                 // oc half: 0/64
    int lrow = lane & 15;
    int lq = lane >> 4;
    int tbase = th * 32;

    f32x4 acc[2][4];
    #pragma unroll
    for (int tt = 0; tt < 2; ++tt)
        #pragma unroll
        for (int n = 0; n < 4; ++n) acc[tt][n] = (f32x4){0.f, 0.f, 0.f, 0.f};

    const u16* ybA = yb + (size_t)b * SEQ * ICD + lq * 8;
    const u16* wfL = wf + (size_t)lane * 8 + ((size_t)nh * 4 * 64) * 8;
    int ks0 = kc * KSPC;

    bf16x8 aA[6], bA[12], aB[6], bB[12];

#define LOAD_AB(aR, bR, KS) do {                                              \
    int kstep_ = ks0 + (KS);                                                  \
    int ic0_ = kstep_ * 32;                                                   \
    _Pragma("unroll")                                                         \
    for (int tt_ = 0; tt_ < 2; ++tt_) {                                       \
        _Pragma("unroll")                                                     \
        for (int w_ = 0; w_ < 3; ++w_) {                                      \
            int ts_ = tbase + tt_ * 16 + lrow + w_ - 1;                       \
            bf16x8 av_ = {0, 0, 0, 0, 0, 0, 0, 0};                            \
            if ((unsigned)ts_ < SEQ)                                          \
                av_ = *(const bf16x8*)(ybA + (size_t)ts_ * ICD + ic0_);       \
            aR[tt_ * 3 + w_] = av_;                                           \
        }                                                                     \
    }                                                                         \
    const u16* wfp_ = wfL + (size_t)kstep_ * WFSTEP;                          \
    _Pragma("unroll")                                                         \
    for (int w_ = 0; w_ < 3; ++w_) {                                          \
        _Pragma("unroll")                                                     \
        for (int n_ = 0; n_ < 4; ++n_)                                        \
            bR[w_ * 4 + n_] = *(const bf16x8*)(wfp_ + (size_t)((w_ * 8 + n_) * 64) * 8); \
    }                                                                         \
} while (0)

#define COMPUTE(aR, bR) do {                                                  \
    _Pragma("unroll")                                                         \
    for (int w_ = 0; w_ < 3; ++w_) {                                          \
        _Pragma("unroll")                                                     \
        for (int tt_ = 0; tt_ < 2; ++tt_) {                                   \
            _Pragma("unroll")                                                 \
            for (int n_ = 0; n_ < 4; ++n_)                                    \
                acc[tt_][n_] = __builtin_amdgcn_mfma_f32_16x16x32_bf16(       \
                    aR[tt_ * 3 + w_], bR[w_ * 4 + n_], acc[tt_][n_], 0, 0, 0);\
        }                                                                     \
    }                                                                         \
} while (0)

    LOAD_AB(aA, bA, 0);
    #pragma unroll
    for (int ks = 0; ks < KSPC - 1; ks += 2) {
        LOAD_AB(aB, bB, ks + 1);
        COMPUTE(aA, bA);
        LOAD_AB(aA, bA, ks + 2);
        COMPUTE(aB, bB);
    }
    COMPUTE(aA, bA);   // ks = KSPC-1 (12)

    float* pp = partial + (size_t)kc * ((size_t)BZ * SEQ * OCN) + (size_t)b * SEQ * OCN + nh * 64;
    #pragma unroll
    for (int tt = 0; tt < 2; ++tt) {
        #pragma unroll
        for (int n = 0; n < 4; ++n) {
            #pragma unroll
            for (int r = 0; r < 4; ++r) {
                int t = tbase + tt * 16 + lq * 4 + r;
                pp[(size_t)t * OCN + n * 16 + lrow] = acc[tt][n][r];
            }
        }
    }
#undef LOAD_AB
#undef COMPUTE
}

// ---------------- split-K reduce (float4) ----------------
__global__ __launch_bounds__(256) void reduce_kernel(const float* __restrict__ partial,
                                                     float* __restrict__ out) {
    int i = (blockIdx.x * 256 + threadIdx.x) * 4;   // 131072 total
    float4 s = make_float4(0.f, 0.f, 0.f, 0.f);
    #pragma unroll
    for (int kc = 0; kc < NKC; ++kc) {
        float4 v = *(const float4*)(partial + (size_t)kc * 131072 + i);
        s.x += v.x; s.y += v.y; s.z += v.z; s.w += v.w;
    }
    *(float4*)(out + i) = s;
}

extern "C" void kernel_launch(void* const* d_in, const int* in_sizes, int n_in,
                              void* d_out, int out_size, void* d_ws, size_t ws_size,
                              hipStream_t stream) {
    const float* x   = (const float*)d_in[0];
    const float* Wq  = (const float*)d_in[1];
    const float* bqv = (const float*)d_in[2];
    const float* Wk  = (const float*)d_in[3];
    const float* bkv = (const float*)d_in[4];
    const float* cw  = (const float*)d_in[5];
    const int* esrc  = (const int*)d_in[6];
    const int* edst  = (const int*)d_in[7];

    char* ws = (char*)d_ws;
    size_t o = 0;
    auto alloc = [&](size_t bytes) {
        void* p = ws + o;
        o += (bytes + 255) & ~(size_t)255;
        return p;
    };
    u16*   xt    = (u16*)alloc(XTOT * 2);                 // 27.1 MB (aliased by partial after gather2)
    u16*   yb    = (u16*)alloc(XTOT * 2);                 // 27.1 MB
    u16*   wf    = (u16*)alloc((size_t)NKPAD * 3 * 8 * 64 * 8 * 2);  // 10.2 MB
    float* meanp = (float*)alloc((size_t)4 * NN * DIN * 4);  // 3.4 MB partial sums
    float* q     = (float*)alloc((size_t)NN * OCN * 4);
    float* k     = (float*)alloc((size_t)NN * OCN * 4);
    int*   fill  = (int*)alloc(4096 * 4);
    int*   offs  = (int*)alloc(4352 * 4);
    int*   csr   = (int*)alloc((size_t)NE * 4);
    float* alpha = (float*)alloc((size_t)NE * 4);
    float* partial = (float*)xt;   // alias: xt dead after gather2; partial live conv->reduce

    histscan_kernel<<<dim3(1), dim3(1024), 0, stream>>>(edst, offs, fill);
    fused3_kernel<<<dim3(CVB + SCB + WPB), dim3(256), 0, stream>>>(x, xt, meanp, esrc, fill, csr, edst, cw, wf);
    qk_kernel<<<dim3(NN / 16), dim3(256), 0, stream>>>(meanp, Wq, bqv, Wk, bkv, q, k);
    alpha_kernel<<<dim3(NN), dim3(256), 0, stream>>>(q, k, offs, csr, alpha);
    gather2_kernel<<<dim3((NN / 4) * NCHUNK), dim3(256), 0, stream>>>(xt, alpha, offs, csr, yb);
    conv_kernel<<<dim3(512), dim3(256), 0, stream>>>(yb, wf, partial);
    reduce_kernel<<<dim3(131072 / 4 / 256), dim3(256), 0, stream>>>(partial, (float*)d_out);
}